// Round 19
// baseline (316.029 us; speedup 1.0000x reference)
//
#include <hip/hip_runtime.h>
#include <math.h>

#define E_EDGES 8192
#define D_FEAT 2048
#define K2 4096   // 2*D
#define H_DIM 128
#define N_NODES 100000
#define SIM_TH 0.7f
#define NSLOTS (2 * E_EDGES)   // 16384 compact slots
#define GBM 16                 // gate edges per block

// ---------------------------------------------------------------------------
// Kernel 1: cosine similarity per edge. One wave (64 lanes) per edge.
// ---------------------------------------------------------------------------
__global__ __launch_bounds__(256) void sim_kernel(const float* __restrict__ xf,
                                                  const float* __restrict__ yf,
                                                  float* __restrict__ sim) {
    int gid  = blockIdx.x * blockDim.x + threadIdx.x;
    int wave = gid >> 6;
    int lane = threadIdx.x & 63;
    if (wave >= E_EDGES) return;
    const float4* xp = (const float4*)(xf + (size_t)wave * D_FEAT);
    const float4* yp = (const float4*)(yf + (size_t)wave * D_FEAT);
    float dot = 0.f, xx = 0.f, yy = 0.f;
#pragma unroll
    for (int j = 0; j < 8; ++j) {
        float4 a = xp[lane + j * 64];
        float4 b = yp[lane + j * 64];
        dot += a.x * b.x + a.y * b.y + a.z * b.z + a.w * b.w;
        xx  += a.x * a.x + a.y * a.y + a.z * a.z + a.w * a.w;
        yy  += b.x * b.x + b.y * b.y + b.z * b.z + b.w * b.w;
    }
#pragma unroll
    for (int off = 32; off; off >>= 1) {
        dot += __shfl_xor(dot, off);
        xx  += __shfl_xor(xx, off);
        yy  += __shfl_xor(yy, off);
    }
    if (lane == 0) {
        float nx = fmaxf(sqrtf(xx), 1e-8f);
        float ny = fmaxf(sqrtf(yy), 1e-8f);
        sim[wave] = dot / (nx * ny);
    }
}

// ---------------------------------------------------------------------------
// Kernel 2: init fo (=INT_MAX), orig (=-1), zero w output.
// ---------------------------------------------------------------------------
__global__ void initmap_kernel(int* __restrict__ fo, int* __restrict__ orig,
                               float* __restrict__ wout) {
    int i = blockIdx.x * blockDim.x + threadIdx.x;
    if (i < N_NODES) fo[i] = 0x7FFFFFFF;
    if (i < NSLOTS)  orig[i] = -1;
    if (i < E_EDGES) wout[i] = 0.f;
}

// ---------------------------------------------------------------------------
// Kernel 3: claim compact slot = first occurrence index in x0,y0,x1,y1,...
// ---------------------------------------------------------------------------
__global__ void claim_kernel(const int* __restrict__ x_idx, const int* __restrict__ y_idx,
                             int* __restrict__ fo) {
    int i = blockIdx.x * blockDim.x + threadIdx.x;
    if (i >= NSLOTS) return;
    int e = i >> 1;
    int v = (i & 1) ? y_idx[e] : x_idx[e];
    atomicMin(&fo[v], i);
}

// ---------------------------------------------------------------------------
// Kernel 4: orig[slot] = node for claimed slots.
// ---------------------------------------------------------------------------
__global__ void orig_kernel(const int* __restrict__ x_idx, const int* __restrict__ y_idx,
                            const int* __restrict__ fo, int* __restrict__ orig) {
    int i = blockIdx.x * blockDim.x + threadIdx.x;
    if (i >= NSLOTS) return;
    int e = i >> 1;
    int v = (i & 1) ? y_idx[e] : x_idx[e];
    if (fo[v] == i) orig[i] = v;
}

// ---------------------------------------------------------------------------
// Kernel 5: order-preserving compaction of masked edges into records
//           rec = {cx, cy, eidx, (w filled later by gate)} + 4 zero pads.
// ---------------------------------------------------------------------------
__global__ __launch_bounds__(256) void maskscan_kernel(
        const int* __restrict__ x_idx, const int* __restrict__ y_idx,
        const int* __restrict__ fo, const float* __restrict__ sim,
        int4* __restrict__ rec, int* __restrict__ nmask) {
    __shared__ int partial[256];
    int t = threadIdx.x;
    int cnt = 0;
    for (int j = 0; j < 32; ++j) {
        int e = t * 32 + j;
        cnt += (sim[e] >= SIM_TH) ? 1 : 0;
    }
    partial[t] = cnt;
    __syncthreads();
    for (int off = 1; off < 256; off <<= 1) {
        int mine  = partial[t];
        int other = (t >= off) ? partial[t - off] : 0;
        __syncthreads();
        partial[t] = mine + other;
        __syncthreads();
    }
    int pos = partial[t] - cnt;
    if (t == 255) {
        int nn = partial[255];
        *nmask = nn;
        for (int j = 0; j < 4; ++j) rec[nn + j] = make_int4(0, 0, 0, 0);
    }
    for (int j = 0; j < 32; ++j) {
        int e = t * 32 + j;
        if (sim[e] >= SIM_TH) {
            int4 r;
            r.x = fo[x_idx[e]];
            r.y = fo[y_idx[e]];
            r.z = e;
            r.w = 0;
            rec[pos++] = r;
        }
    }
}

// ---------------------------------------------------------------------------
// Kernel 6a: gate MLP split kernel — grid (512, NH).  Block (bx, h) computes
//   partial dot products for 16 edges over K-segment h (klen = K2/NH).
//   Per-wave structure, fma:LDS ratio, total W1 traffic identical to the
//   measured-good v3; NH=4 -> 1024 active blocks -> 4 blocks/CU (LDS 153.6
//   of 160 KB, VGPR 116*4=464 of 512 -> fits).  Partials -> pbuf[e][h][128].
// ---------------------------------------------------------------------------
__global__ __launch_bounds__(256) void gate_split_kernel(
        const float* __restrict__ xf, const float* __restrict__ yf,
        const float* __restrict__ W1,
        const int4* __restrict__ rec, const int* __restrict__ nmask,
        float* __restrict__ pbuf) {
    __shared__ float As[2][GBM][32];       //  4 KB
    __shared__ float Bs[2][H_DIM][33];     // 33.8 KB (pitch 33)
    __shared__ int   elds[GBM];

    int n  = *nmask;
    int b0 = blockIdx.x * GBM;
    if (b0 >= n) return;
    const int nh     = gridDim.y;
    const int h      = blockIdx.y;
    const int klen   = K2 / nh;
    const int kstart = h * klen;

    int t = threadIdx.x;
    if (t < GBM) {
        int idx = b0 + t;
        elds[t] = (idx < n) ? rec[idx].z : rec[b0].z;
    }
    __syncthreads();

    const int  arow = t >> 3;
    const int  acol = (t & 7) * 4;
    const bool aact = (t < 128);
    const int  brow = t >> 3;
    const int  bcol = (t & 7) * 4;

    const float* feat = (kstart < D_FEAT) ? xf : yf;
    const int    foff = kstart & (D_FEAT - 1);
    const float* arp  = feat + (size_t)elds[aact ? arow : 0] * D_FEAT + foff + acol;
    const float* w1p0 = W1 + (size_t)(brow +  0) * K2 + kstart + bcol;
    const float* w1p1 = W1 + (size_t)(brow + 32) * K2 + kstart + bcol;
    const float* w1p2 = W1 + (size_t)(brow + 64) * K2 + kstart + bcol;
    const float* w1p3 = W1 + (size_t)(brow + 96) * K2 + kstart + bcol;

    float4 aR = make_float4(0.f, 0.f, 0.f, 0.f);
    float4 bR0, bR1, bR2, bR3;

    if (aact) aR = *(const float4*)(arp + 0);
    bR0 = *(const float4*)(w1p0 + 0);
    bR1 = *(const float4*)(w1p1 + 0);
    bR2 = *(const float4*)(w1p2 + 0);
    bR3 = *(const float4*)(w1p3 + 0);
    if (aact) *(float4*)(&As[0][arow][acol]) = aR;
    Bs[0][brow +  0][bcol + 0] = bR0.x; Bs[0][brow +  0][bcol + 1] = bR0.y;
    Bs[0][brow +  0][bcol + 2] = bR0.z; Bs[0][brow +  0][bcol + 3] = bR0.w;
    Bs[0][brow + 32][bcol + 0] = bR1.x; Bs[0][brow + 32][bcol + 1] = bR1.y;
    Bs[0][brow + 32][bcol + 2] = bR1.z; Bs[0][brow + 32][bcol + 3] = bR1.w;
    Bs[0][brow + 64][bcol + 0] = bR2.x; Bs[0][brow + 64][bcol + 1] = bR2.y;
    Bs[0][brow + 64][bcol + 2] = bR2.z; Bs[0][brow + 64][bcol + 3] = bR2.w;
    Bs[0][brow + 96][bcol + 0] = bR3.x; Bs[0][brow + 96][bcol + 1] = bR3.y;
    Bs[0][brow + 96][bcol + 2] = bR3.z; Bs[0][brow + 96][bcol + 3] = bR3.w;
    __syncthreads();

    const int eb = (t >> 6) * 4;
    const int ln = t & 63;
    float acc[4][2] = {{0.f,0.f},{0.f,0.f},{0.f,0.f},{0.f,0.f}};

    const int NT = klen / 32;
    for (int tile = 0; tile < NT; ++tile) {
        const int buf = tile & 1;
        if (tile + 1 < NT) {
            int k0 = (tile + 1) * 32;
            if (aact) aR = *(const float4*)(arp + k0);
            bR0 = *(const float4*)(w1p0 + k0);
            bR1 = *(const float4*)(w1p1 + k0);
            bR2 = *(const float4*)(w1p2 + k0);
            bR3 = *(const float4*)(w1p3 + k0);
        }
#pragma unroll
        for (int kk = 0; kk < 32; kk += 4) {
            float4 a0 = *(const float4*)(&As[buf][eb + 0][kk]);
            float4 a1 = *(const float4*)(&As[buf][eb + 1][kk]);
            float4 a2 = *(const float4*)(&As[buf][eb + 2][kk]);
            float4 a3 = *(const float4*)(&As[buf][eb + 3][kk]);
            float bl0 = Bs[buf][ln][kk + 0];
            float bl1 = Bs[buf][ln][kk + 1];
            float bl2 = Bs[buf][ln][kk + 2];
            float bl3 = Bs[buf][ln][kk + 3];
            float bh0 = Bs[buf][ln + 64][kk + 0];
            float bh1 = Bs[buf][ln + 64][kk + 1];
            float bh2 = Bs[buf][ln + 64][kk + 2];
            float bh3 = Bs[buf][ln + 64][kk + 3];
            acc[0][0] = fmaf(a0.x, bl0, acc[0][0]);
            acc[0][0] = fmaf(a0.y, bl1, acc[0][0]);
            acc[0][0] = fmaf(a0.z, bl2, acc[0][0]);
            acc[0][0] = fmaf(a0.w, bl3, acc[0][0]);
            acc[0][1] = fmaf(a0.x, bh0, acc[0][1]);
            acc[0][1] = fmaf(a0.y, bh1, acc[0][1]);
            acc[0][1] = fmaf(a0.z, bh2, acc[0][1]);
            acc[0][1] = fmaf(a0.w, bh3, acc[0][1]);
            acc[1][0] = fmaf(a1.x, bl0, acc[1][0]);
            acc[1][0] = fmaf(a1.y, bl1, acc[1][0]);
            acc[1][0] = fmaf(a1.z, bl2, acc[1][0]);
            acc[1][0] = fmaf(a1.w, bl3, acc[1][0]);
            acc[1][1] = fmaf(a1.x, bh0, acc[1][1]);
            acc[1][1] = fmaf(a1.y, bh1, acc[1][1]);
            acc[1][1] = fmaf(a1.z, bh2, acc[1][1]);
            acc[1][1] = fmaf(a1.w, bh3, acc[1][1]);
            acc[2][0] = fmaf(a2.x, bl0, acc[2][0]);
            acc[2][0] = fmaf(a2.y, bl1, acc[2][0]);
            acc[2][0] = fmaf(a2.z, bl2, acc[2][0]);
            acc[2][0] = fmaf(a2.w, bl3, acc[2][0]);
            acc[2][1] = fmaf(a2.x, bh0, acc[2][1]);
            acc[2][1] = fmaf(a2.y, bh1, acc[2][1]);
            acc[2][1] = fmaf(a2.z, bh2, acc[2][1]);
            acc[2][1] = fmaf(a2.w, bh3, acc[2][1]);
            acc[3][0] = fmaf(a3.x, bl0, acc[3][0]);
            acc[3][0] = fmaf(a3.y, bl1, acc[3][0]);
            acc[3][0] = fmaf(a3.z, bl2, acc[3][0]);
            acc[3][0] = fmaf(a3.w, bl3, acc[3][0]);
            acc[3][1] = fmaf(a3.x, bh0, acc[3][1]);
            acc[3][1] = fmaf(a3.y, bh1, acc[3][1]);
            acc[3][1] = fmaf(a3.z, bh2, acc[3][1]);
            acc[3][1] = fmaf(a3.w, bh3, acc[3][1]);
        }
        if (tile + 1 < NT) {
            const int nb = buf ^ 1;
            if (aact) *(float4*)(&As[nb][arow][acol]) = aR;
            Bs[nb][brow +  0][bcol + 0] = bR0.x; Bs[nb][brow +  0][bcol + 1] = bR0.y;
            Bs[nb][brow +  0][bcol + 2] = bR0.z; Bs[nb][brow +  0][bcol + 3] = bR0.w;
            Bs[nb][brow + 32][bcol + 0] = bR1.x; Bs[nb][brow + 32][bcol + 1] = bR1.y;
            Bs[nb][brow + 32][bcol + 2] = bR1.z; Bs[nb][brow + 32][bcol + 3] = bR1.w;
            Bs[nb][brow + 64][bcol + 0] = bR2.x; Bs[nb][brow + 64][bcol + 1] = bR2.y;
            Bs[nb][brow + 64][bcol + 2] = bR2.z; Bs[nb][brow + 64][bcol + 3] = bR2.w;
            Bs[nb][brow + 96][bcol + 0] = bR3.x; Bs[nb][brow + 96][bcol + 1] = bR3.y;
            Bs[nb][brow + 96][bcol + 2] = bR3.z; Bs[nb][brow + 96][bcol + 3] = bR3.w;
        }
        __syncthreads();
    }

    // ---- write partials ----
#pragma unroll
    for (int j = 0; j < 4; ++j) {
        float* pb = pbuf + (((size_t)(b0 + eb + j) * nh + h) << 7);
        pb[ln]      = acc[j][0];
        pb[ln + 64] = acc[j][1];
    }
}

// ---------------------------------------------------------------------------
// Kernel 6b: gate epilogue — h = relu(sum_h p_h + b1) (fixed h order), then
//   the exact legacy W2 chain, sigmoid; fills w_out and rec.w.
// ---------------------------------------------------------------------------
__global__ __launch_bounds__(256) void gate_fin_kernel(
        const float* __restrict__ pbuf, const float* __restrict__ b1,
        const float* __restrict__ W2, const float* __restrict__ b2,
        int4* __restrict__ rec, const int* __restrict__ nmask,
        float* __restrict__ wout, int nh) {
    int e = blockIdx.x * blockDim.x + threadIdx.x;
    if (e >= *nmask) return;
    const float* p0 = pbuf + ((size_t)e * nh << 7);
    float s = 0.f;
    for (int c = 0; c < 32; ++c) {
        float p = 0.f;
#pragma unroll
        for (int q = 0; q < 4; ++q) {
            int nn = 4 * c + q;
            float hh = p0[nn];
            for (int hidx = 1; hidx < nh; ++hidx) hh += p0[(hidx << 7) + nn];
            hh = fmaxf(hh + b1[nn], 0.f);
            p = fmaf(hh, W2[nn], p);
        }
        s += p;
    }
    float logit = s + b2[0];
    float attn  = 1.f / (1.f + expf(-logit));
    wout[rec[e].z] = attn;
    ((int*)&rec[e])[3] = __float_as_int(attn);
}

// ---------------------------------------------------------------------------
// Kernel 6-fallback: gate MLP v3 single-kernel (measured 160 us) — used when
//   ws_size is too small for the partial buffer.
// ---------------------------------------------------------------------------
__global__ __launch_bounds__(256) void gate_v3_kernel(
        const float* __restrict__ xf, const float* __restrict__ yf,
        const float* __restrict__ W1, const float* __restrict__ b1,
        const float* __restrict__ W2, const float* __restrict__ b2,
        int4* __restrict__ rec, const int* __restrict__ nmask,
        float* __restrict__ wout) {
    __shared__ float As[2][GBM][32];
    __shared__ float Bs[2][H_DIM][33];
    __shared__ float hbuf[GBM][132];
    __shared__ int   elds[GBM];

    int n  = *nmask;
    int b0 = blockIdx.x * GBM;
    if (b0 >= n) return;

    int t = threadIdx.x;
    if (t < GBM) {
        int idx = b0 + t;
        elds[t] = (idx < n) ? rec[idx].z : rec[b0].z;
    }
    __syncthreads();

    const int  arow = t >> 3;
    const int  acol = (t & 7) * 4;
    const bool aact = (t < 128);
    const int  brow = t >> 3;
    const int  bcol = (t & 7) * 4;

    const float* xrow = xf + (size_t)elds[aact ? arow : 0] * D_FEAT + acol;
    const float* yrow = yf + (size_t)elds[aact ? arow : 0] * D_FEAT + acol;
    const float* w1p0 = W1 + (size_t)(brow +  0) * K2 + bcol;
    const float* w1p1 = W1 + (size_t)(brow + 32) * K2 + bcol;
    const float* w1p2 = W1 + (size_t)(brow + 64) * K2 + bcol;
    const float* w1p3 = W1 + (size_t)(brow + 96) * K2 + bcol;

    float4 aR = make_float4(0.f, 0.f, 0.f, 0.f);
    float4 bR0, bR1, bR2, bR3;

    if (aact) aR = *(const float4*)(xrow + 0);
    bR0 = *(const float4*)(w1p0 + 0);
    bR1 = *(const float4*)(w1p1 + 0);
    bR2 = *(const float4*)(w1p2 + 0);
    bR3 = *(const float4*)(w1p3 + 0);
    if (aact) *(float4*)(&As[0][arow][acol]) = aR;
    Bs[0][brow +  0][bcol + 0] = bR0.x; Bs[0][brow +  0][bcol + 1] = bR0.y;
    Bs[0][brow +  0][bcol + 2] = bR0.z; Bs[0][brow +  0][bcol + 3] = bR0.w;
    Bs[0][brow + 32][bcol + 0] = bR1.x; Bs[0][brow + 32][bcol + 1] = bR1.y;
    Bs[0][brow + 32][bcol + 2] = bR1.z; Bs[0][brow + 32][bcol + 3] = bR1.w;
    Bs[0][brow + 64][bcol + 0] = bR2.x; Bs[0][brow + 64][bcol + 1] = bR2.y;
    Bs[0][brow + 64][bcol + 2] = bR2.z; Bs[0][brow + 64][bcol + 3] = bR2.w;
    Bs[0][brow + 96][bcol + 0] = bR3.x; Bs[0][brow + 96][bcol + 1] = bR3.y;
    Bs[0][brow + 96][bcol + 2] = bR3.z; Bs[0][brow + 96][bcol + 3] = bR3.w;
    __syncthreads();

    const int eb = (t >> 6) * 4;
    const int ln = t & 63;
    float acc[4][2] = {{0.f,0.f},{0.f,0.f},{0.f,0.f},{0.f,0.f}};

    const int NT = K2 / 32;
    for (int tile = 0; tile < NT; ++tile) {
        const int buf = tile & 1;
        if (tile + 1 < NT) {
            int k0 = (tile + 1) * 32;
            if (aact) {
                const float* ap = (k0 < D_FEAT) ? (xrow + k0) : (yrow + (k0 - D_FEAT));
                aR = *(const float4*)ap;
            }
            bR0 = *(const float4*)(w1p0 + k0);
            bR1 = *(const float4*)(w1p1 + k0);
            bR2 = *(const float4*)(w1p2 + k0);
            bR3 = *(const float4*)(w1p3 + k0);
        }
#pragma unroll
        for (int kk = 0; kk < 32; kk += 4) {
            float4 a0 = *(const float4*)(&As[buf][eb + 0][kk]);
            float4 a1 = *(const float4*)(&As[buf][eb + 1][kk]);
            float4 a2 = *(const float4*)(&As[buf][eb + 2][kk]);
            float4 a3 = *(const float4*)(&As[buf][eb + 3][kk]);
            float bl0 = Bs[buf][ln][kk + 0];
            float bl1 = Bs[buf][ln][kk + 1];
            float bl2 = Bs[buf][ln][kk + 2];
            float bl3 = Bs[buf][ln][kk + 3];
            float bh0 = Bs[buf][ln + 64][kk + 0];
            float bh1 = Bs[buf][ln + 64][kk + 1];
            float bh2 = Bs[buf][ln + 64][kk + 2];
            float bh3 = Bs[buf][ln + 64][kk + 3];
            acc[0][0] = fmaf(a0.x, bl0, acc[0][0]);
            acc[0][0] = fmaf(a0.y, bl1, acc[0][0]);
            acc[0][0] = fmaf(a0.z, bl2, acc[0][0]);
            acc[0][0] = fmaf(a0.w, bl3, acc[0][0]);
            acc[0][1] = fmaf(a0.x, bh0, acc[0][1]);
            acc[0][1] = fmaf(a0.y, bh1, acc[0][1]);
            acc[0][1] = fmaf(a0.z, bh2, acc[0][1]);
            acc[0][1] = fmaf(a0.w, bh3, acc[0][1]);
            acc[1][0] = fmaf(a1.x, bl0, acc[1][0]);
            acc[1][0] = fmaf(a1.y, bl1, acc[1][0]);
            acc[1][0] = fmaf(a1.z, bl2, acc[1][0]);
            acc[1][0] = fmaf(a1.w, bl3, acc[1][0]);
            acc[1][1] = fmaf(a1.x, bh0, acc[1][1]);
            acc[1][1] = fmaf(a1.y, bh1, acc[1][1]);
            acc[1][1] = fmaf(a1.z, bh2, acc[1][1]);
            acc[1][1] = fmaf(a1.w, bh3, acc[1][1]);
            acc[2][0] = fmaf(a2.x, bl0, acc[2][0]);
            acc[2][0] = fmaf(a2.y, bl1, acc[2][0]);
            acc[2][0] = fmaf(a2.z, bl2, acc[2][0]);
            acc[2][0] = fmaf(a2.w, bl3, acc[2][0]);
            acc[2][1] = fmaf(a2.x, bh0, acc[2][1]);
            acc[2][1] = fmaf(a2.y, bh1, acc[2][1]);
            acc[2][1] = fmaf(a2.z, bh2, acc[2][1]);
            acc[2][1] = fmaf(a2.w, bh3, acc[2][1]);
            acc[3][0] = fmaf(a3.x, bl0, acc[3][0]);
            acc[3][0] = fmaf(a3.y, bl1, acc[3][0]);
            acc[3][0] = fmaf(a3.z, bl2, acc[3][0]);
            acc[3][0] = fmaf(a3.w, bl3, acc[3][0]);
            acc[3][1] = fmaf(a3.x, bh0, acc[3][1]);
            acc[3][1] = fmaf(a3.y, bh1, acc[3][1]);
            acc[3][1] = fmaf(a3.z, bh2, acc[3][1]);
            acc[3][1] = fmaf(a3.w, bh3, acc[3][1]);
        }
        if (tile + 1 < NT) {
            const int nb = buf ^ 1;
            if (aact) *(float4*)(&As[nb][arow][acol]) = aR;
            Bs[nb][brow +  0][bcol + 0] = bR0.x; Bs[nb][brow +  0][bcol + 1] = bR0.y;
            Bs[nb][brow +  0][bcol + 2] = bR0.z; Bs[nb][brow +  0][bcol + 3] = bR0.w;
            Bs[nb][brow + 32][bcol + 0] = bR1.x; Bs[nb][brow + 32][bcol + 1] = bR1.y;
            Bs[nb][brow + 32][bcol + 2] = bR1.z; Bs[nb][brow + 32][bcol + 3] = bR1.w;
            Bs[nb][brow + 64][bcol + 0] = bR2.x; Bs[nb][brow + 64][bcol + 1] = bR2.y;
            Bs[nb][brow + 64][bcol + 2] = bR2.z; Bs[nb][brow + 64][bcol + 3] = bR2.w;
            Bs[nb][brow + 96][bcol + 0] = bR3.x; Bs[nb][brow + 96][bcol + 1] = bR3.y;
            Bs[nb][brow + 96][bcol + 2] = bR3.z; Bs[nb][brow + 96][bcol + 3] = bR3.w;
        }
        __syncthreads();
    }

#pragma unroll
    for (int j = 0; j < 4; ++j) {
        hbuf[eb + j][ln]      = fmaxf(acc[j][0] + b1[ln], 0.f);
        hbuf[eb + j][ln + 64] = fmaxf(acc[j][1] + b1[ln + 64], 0.f);
    }
    __syncthreads();
    if (t < GBM && b0 + t < n) {
        float s = 0.f;
        for (int c = 0; c < 32; ++c) {
            float p = 0.f;
#pragma unroll
            for (int q = 0; q < 4; ++q)
                p = fmaf(hbuf[t][4 * c + q], W2[4 * c + q], p);
            s += p;
        }
        float logit = s + b2[0];
        float attn  = 1.f / (1.f + expf(-logit));
        wout[elds[t]] = attn;
        ((int*)&rec[b0 + t])[3] = __float_as_int(attn);
    }
}

// ---------------------------------------------------------------------------
// Kernel 7: CC labels (min-label fixpoint in LDS) -> per-EDGE labels elab[].
// ---------------------------------------------------------------------------
__global__ __launch_bounds__(1024) void label_kernel(
        const int4* __restrict__ rec, const int* __restrict__ nmask,
        int* __restrict__ elab) {
    extern __shared__ int L[];
    int t = threadIdx.x;
    int n = *nmask;
    for (int c = t; c < NSLOTS; c += 1024) L[c] = c;
    __syncthreads();
    for (;;) {
        if (t == 0) L[NSLOTS] = 0;
        __syncthreads();
        for (int e = t; e < n; e += 1024) {
            int4 r = rec[e];
            int a = L[r.x], b = L[r.y];
            if (a < b)      { atomicMin(&L[r.y], a); L[NSLOTS] = 1; }
            else if (b < a) { atomicMin(&L[r.x], b); L[NSLOTS] = 1; }
        }
        __syncthreads();
        if (!L[NSLOTS]) break;
        __syncthreads();
        for (int c = t; c < NSLOTS; c += 1024) {
            int q  = L[c];
            int qq = L[q];
            if (qq < q) L[c] = qq;
        }
        __syncthreads();
    }
    __syncthreads();
    for (int e = t; e < n; e += 1024) elab[e] = L[rec[e].x];
}

// ---------------------------------------------------------------------------
// Kernel 8: stable LSD radix sort of edges by CC label (4 passes x 4 bits),
//   single block, 1024 threads; then boundary extraction.
// ---------------------------------------------------------------------------
__global__ __launch_bounds__(1024) void radix_kernel(
        int4* __restrict__ bufA, int4* __restrict__ bufB,
        int* __restrict__ keyA, int* __restrict__ keyB,
        const int* __restrict__ nmask,
        int* __restrict__ compStart, int* __restrict__ ncompOut) {
    __shared__ int F[16384];
    __shared__ int P[1024];
    int t = threadIdx.x;
    int n = *nmask;
    int c = (n + 1023) >> 10;

    for (int pass = 0; pass < 4; ++pass) {
        int sh = pass * 4;
        const int4* in   = (pass & 1) ? bufB : bufA;
        int4*       out  = (pass & 1) ? bufA : bufB;
        const int*  kin  = (pass & 1) ? keyB : keyA;
        int*        kout = (pass & 1) ? keyA : keyB;
        for (int q = 0; q < 16; ++q) F[t * 16 + q] = 0;
        __syncthreads();
        for (int j = 0; j < c; ++j) {
            int i = t * c + j;
            if (i < n) {
                int d = (kin[i] >> sh) & 15;
                F[d * 1024 + t] += 1;
            }
        }
        __syncthreads();
        int base = t * 16;
        int loc[16]; int s = 0;
#pragma unroll
        for (int q = 0; q < 16; ++q) { loc[q] = s; s += F[base + q]; }
        P[t] = s;
        __syncthreads();
        for (int off = 1; off < 1024; off <<= 1) {
            int mine  = P[t];
            int other = (t >= off) ? P[t - off] : 0;
            __syncthreads();
            P[t] = mine + other;
            __syncthreads();
        }
        int pre = (t == 0) ? 0 : P[t - 1];
#pragma unroll
        for (int q = 0; q < 16; ++q) F[base + q] = pre + loc[q];
        __syncthreads();
        for (int j = 0; j < c; ++j) {
            int i = t * c + j;
            if (i < n) {
                int k = kin[i];
                int d = (k >> sh) & 15;
                int pos = F[d * 1024 + t]++;
                out[pos]  = in[i];
                kout[pos] = k;
            }
        }
        __syncthreads();
    }

    unsigned char* hd = (unsigned char*)F;
    for (int i = t; i < n; i += 1024) {
        int l  = keyA[i];
        int lp = (i == 0) ? -1 : keyA[i - 1];
        hd[i] = (l != lp) ? 1 : 0;
    }
    __syncthreads();
    int hsum = 0;
    for (int j = 0; j < c; ++j) {
        int i = t * c + j;
        if (i < n) hsum += hd[i];
    }
    P[t] = hsum;
    __syncthreads();
    for (int off = 1; off < 1024; off <<= 1) {
        int mine  = P[t];
        int other = (t >= off) ? P[t - off] : 0;
        __syncthreads();
        P[t] = mine + other;
        __syncthreads();
    }
    int run = P[t] - hsum;
    for (int j = 0; j < c; ++j) {
        int i = t * c + j;
        if (i < n && hd[i]) { compStart[run] = i; ++run; }
    }
    if (t == 1023) { int total = P[1023]; *ncompOut = total; compStart[total] = n; }
}

// ---------------------------------------------------------------------------
// Kernel 9: exact union-find, parallel over connected components.
// ---------------------------------------------------------------------------
__global__ __launch_bounds__(1024) void uf_kernel(
        const int4* __restrict__ srec, const int* __restrict__ ncompPtr,
        const int* __restrict__ compStart,
        const int* __restrict__ orig, const float* __restrict__ rin,
        int* __restrict__ gpar, float* __restrict__ grank) {
    extern __shared__ char smem[];
    int2* nd = (int2*)smem;
    int* ndw = (int*)smem;
    int t = threadIdx.x;
    for (int c = t; c < NSLOTS; c += 1024) {
        int o = orig[c];
        float r = (o >= 0) ? rin[o] : 1.0f;
        nd[c] = make_int2(c, __float_as_int(r));
    }
    __syncthreads();

    int ncomp = *ncompPtr;
    for (int c = t; c < ncomp; c += 1024) {
        int s  = compStart[c];
        int en = compStart[c + 1];
        for (int j = s; j < en; ++j) {
            int4 r = srec[j];
            int x = r.x, y = r.y;
            float wi = __int_as_float(r.w);
            int p;
            int rx = x;
            while ((p = ndw[rx * 2]) != rx) rx = p;
            int j2 = x;
            while ((p = ndw[j2 * 2]) != rx) { ndw[j2 * 2] = rx; j2 = p; }
            int ry = y;
            while ((p = ndw[ry * 2]) != ry) ry = p;
            j2 = y;
            while ((p = ndw[j2 * 2]) != ry) { ndw[j2 * 2] = ry; j2 = p; }
            if (rx != ry) {
                float ka = __int_as_float(ndw[rx * 2 + 1]);
                float kb = __int_as_float(ndw[ry * 2 + 1]);
                bool bx = ka > kb;
                int big = bx ? rx : ry, small = bx ? ry : rx;
                float nr = bx ? (ka + kb * wi) : (kb + ka * wi);
                ndw[small * 2]   = big;
                ndw[big * 2 + 1] = __float_as_int(nr);
            }
        }
    }
    __syncthreads();
    for (int c = t; c < NSLOTS; c += 1024) {
        int2 v = nd[c];
        gpar[c] = v.x;
        grank[c] = __int_as_float(v.y);
    }
}

// ---------------------------------------------------------------------------
// Kernel 10: finalize — per node, claimed -> compact result, else input copy.
// ---------------------------------------------------------------------------
__global__ void finalize_kernel(const int* __restrict__ pin, const float* __restrict__ rin,
                                const int* __restrict__ fo, const int* __restrict__ orig,
                                const int* __restrict__ gpar, const float* __restrict__ grank,
                                float* __restrict__ pout, float* __restrict__ rout) {
    int i = blockIdx.x * blockDim.x + threadIdx.x;
    if (i >= N_NODES) return;
    int c = fo[i];
    float pv, rv;
    if (c != 0x7FFFFFFF) {
        pv = (float)orig[gpar[c]];
        rv = grank[c];
    } else {
        pv = (float)pin[i];
        rv = rin[i];
    }
    pout[i] = pv;
    rout[i] = rv;
}

// ---------------------------------------------------------------------------
extern "C" void kernel_launch(void* const* d_in, const int* in_sizes, int n_in,
                              void* d_out, int out_size, void* d_ws, size_t ws_size,
                              hipStream_t stream) {
    const int*   x_idx = (const int*)d_in[0];
    const int*   y_idx = (const int*)d_in[1];
    const float* xf    = (const float*)d_in[2];
    const float* yf    = (const float*)d_in[3];
    const float* W1    = (const float*)d_in[4];
    const float* b1    = (const float*)d_in[5];
    const float* W2    = (const float*)d_in[6];
    const float* b2    = (const float*)d_in[7];
    const int*   pin   = (const int*)d_in[8];
    const float* rin   = (const float*)d_in[9];

    float* out   = (float*)d_out;
    float* w_out = out;                        // [E]
    float* pout  = out + E_EDGES;              // [N]
    float* rout  = out + E_EDGES + N_NODES;    // [N]

    char* ws = (char*)d_ws;
    float* sim_ws  = (float*)(ws + 0);         //  32768 B (later: keyA)
    int*   fo      = (int*)  (ws + 32768);     // 400000 B
    int*   orig    = (int*)  (ws + 432768);    //  65536 B
    int4*  rec     = (int4*) (ws + 498304);    // 131136 B  (8192+4 recs)
    int*   nmask   = (int*)  (ws + 629440);    //     64 B
    int*   gpar    = (int*)  (ws + 629504);    //  65536 B
    float* grank   = (float*)(ws + 695040);    //  65536 B
    int4*  srec    = (int4*) (ws + 760576);    // 131072 B (radix scratch)
    int*   keyB    = (int*)  (ws + 891648);    //  32768 B
    int*   compSt  = (int*)  (ws + 924416);    //  32772 B (8193 ints)
    int*   ncomp   = (int*)  (ws + 957188);    //      4 B
    float* pbuf    = (float*)(ws + 957440);    // partials (if ws allows)
    int*   keyA    = (int*)sim_ws;             // overlay: sim consumed by maskscan

    const size_t need2 = 957440 + (size_t)E_EDGES * 2 * 128 * sizeof(float);
    const size_t need4 = 957440 + (size_t)E_EDGES * 4 * 128 * sizeof(float);

    // 1) cosine sim
    sim_kernel<<<(E_EDGES * 64) / 256, 256, 0, stream>>>(xf, yf, sim_ws);
    // 2) compact-id mapping + zero w
    int g = (N_NODES + 255) / 256;
    initmap_kernel<<<g, 256, 0, stream>>>(fo, orig, w_out);
    claim_kernel<<<NSLOTS / 256, 256, 0, stream>>>(x_idx, y_idx, fo);
    orig_kernel<<<NSLOTS / 256, 256, 0, stream>>>(x_idx, y_idx, fo, orig);
    // 3) masked-edge compaction (records + padding)
    maskscan_kernel<<<1, 256, 0, stream>>>(x_idx, y_idx, fo, sim_ws, rec, nmask);
    // 4) gate MLP over masked edges (K-split x4 / x2 / fallback by ws_size)
    if (ws_size >= need4) {
        dim3 gg(E_EDGES / GBM, 4);
        gate_split_kernel<<<gg, 256, 0, stream>>>(xf, yf, W1, rec, nmask, pbuf);
        gate_fin_kernel<<<E_EDGES / 256, 256, 0, stream>>>(pbuf, b1, W2, b2,
                                                           rec, nmask, w_out, 4);
    } else if (ws_size >= need2) {
        dim3 gg(E_EDGES / GBM, 2);
        gate_split_kernel<<<gg, 256, 0, stream>>>(xf, yf, W1, rec, nmask, pbuf);
        gate_fin_kernel<<<E_EDGES / 256, 256, 0, stream>>>(pbuf, b1, W2, b2,
                                                           rec, nmask, w_out, 2);
    } else {
        gate_v3_kernel<<<E_EDGES / GBM, 256, 0, stream>>>(xf, yf, W1, b1, W2, b2,
                                                          rec, nmask, w_out);
    }
    // 5) CC labels per edge (deterministic min-label fixpoint)
    label_kernel<<<1, 1024, (NSLOTS + 1) * sizeof(int), stream>>>(rec, nmask, keyA);
    // 6) stable radix sort by label + boundaries (single block)
    radix_kernel<<<1, 1024, 0, stream>>>(rec, srec, keyA, keyB, nmask, compSt, ncomp);
    // 7) exact UF, parallel over components (LDS 128 KB); sorted edges in rec
    uf_kernel<<<1, 1024, 131072, stream>>>(rec, ncomp, compSt, orig, rin, gpar, grank);
    // 8) finalize outputs (base copy + compact scatter fused)
    finalize_kernel<<<g, 256, 0, stream>>>(pin, rin, fo, orig, gpar, grank, pout, rout);
}

// Round 20
// 274.486 us; speedup vs baseline: 1.1513x; 1.1513x over previous
//
#include <hip/hip_runtime.h>
#include <math.h>

#define E_EDGES 8192
#define D_FEAT 2048
#define K2 4096   // 2*D
#define H_DIM 128
#define N_NODES 100000
#define SIM_TH 0.7f
#define NSLOTS (2 * E_EDGES)   // 16384 compact slots
#define GBM 16                 // gate edges per block

// ---------------------------------------------------------------------------
// Kernel 1: cosine similarity per edge. One wave (64 lanes) per edge.
// ---------------------------------------------------------------------------
__global__ __launch_bounds__(256) void sim_kernel(const float* __restrict__ xf,
                                                  const float* __restrict__ yf,
                                                  float* __restrict__ sim) {
    int gid  = blockIdx.x * blockDim.x + threadIdx.x;
    int wave = gid >> 6;
    int lane = threadIdx.x & 63;
    if (wave >= E_EDGES) return;
    const float4* xp = (const float4*)(xf + (size_t)wave * D_FEAT);
    const float4* yp = (const float4*)(yf + (size_t)wave * D_FEAT);
    float dot = 0.f, xx = 0.f, yy = 0.f;
#pragma unroll
    for (int j = 0; j < 8; ++j) {
        float4 a = xp[lane + j * 64];
        float4 b = yp[lane + j * 64];
        dot += a.x * b.x + a.y * b.y + a.z * b.z + a.w * b.w;
        xx  += a.x * a.x + a.y * a.y + a.z * a.z + a.w * a.w;
        yy  += b.x * b.x + b.y * b.y + b.z * b.z + b.w * b.w;
    }
#pragma unroll
    for (int off = 32; off; off >>= 1) {
        dot += __shfl_xor(dot, off);
        xx  += __shfl_xor(xx, off);
        yy  += __shfl_xor(yy, off);
    }
    if (lane == 0) {
        float nx = fmaxf(sqrtf(xx), 1e-8f);
        float ny = fmaxf(sqrtf(yy), 1e-8f);
        sim[wave] = dot / (nx * ny);
    }
}

// ---------------------------------------------------------------------------
// Kernel 2: init fo (=INT_MAX), orig (=-1), zero w output.
// ---------------------------------------------------------------------------
__global__ void initmap_kernel(int* __restrict__ fo, int* __restrict__ orig,
                               float* __restrict__ wout) {
    int i = blockIdx.x * blockDim.x + threadIdx.x;
    if (i < N_NODES) fo[i] = 0x7FFFFFFF;
    if (i < NSLOTS)  orig[i] = -1;
    if (i < E_EDGES) wout[i] = 0.f;
}

// ---------------------------------------------------------------------------
// Kernel 3: claim compact slot = first occurrence index in x0,y0,x1,y1,...
// ---------------------------------------------------------------------------
__global__ void claim_kernel(const int* __restrict__ x_idx, const int* __restrict__ y_idx,
                             int* __restrict__ fo) {
    int i = blockIdx.x * blockDim.x + threadIdx.x;
    if (i >= NSLOTS) return;
    int e = i >> 1;
    int v = (i & 1) ? y_idx[e] : x_idx[e];
    atomicMin(&fo[v], i);
}

// ---------------------------------------------------------------------------
// Kernel 4: orig[slot] = node for claimed slots.
// ---------------------------------------------------------------------------
__global__ void orig_kernel(const int* __restrict__ x_idx, const int* __restrict__ y_idx,
                            const int* __restrict__ fo, int* __restrict__ orig) {
    int i = blockIdx.x * blockDim.x + threadIdx.x;
    if (i >= NSLOTS) return;
    int e = i >> 1;
    int v = (i & 1) ? y_idx[e] : x_idx[e];
    if (fo[v] == i) orig[i] = v;
}

// ---------------------------------------------------------------------------
// Kernel 5 (MERGED): maskscan + CC-label + stable radix sort + boundaries,
//   one 1024-thread block, phases share 136 KB dynamic LDS:
//     keys0 [0,32K)  keys1 [32K,64K)  C [64K,128K) (L / F / hd)  P [128K,136K)
//   Phase 0: order-preserving compaction of masked edges into rec.
//   Phase 1: min-label fixpoint (deterministic) -> keys0[e] = label.
//   Phase 2: 4x4-bit stable LSD radix by label (keys in LDS, recs global,
//            rec->srec->rec->srec->rec).
//   Phase 3: head-flag boundary extraction -> compStart[], ncomp.
// ---------------------------------------------------------------------------
__global__ __launch_bounds__(1024) void sortprep_kernel(
        const int* __restrict__ x_idx, const int* __restrict__ y_idx,
        const int* __restrict__ fo, const float* __restrict__ sim,
        int4* __restrict__ rec, int4* __restrict__ srec,
        int* __restrict__ nmask, int* __restrict__ compStart,
        int* __restrict__ ncompOut) {
    extern __shared__ char sm[];
    int* keys0 = (int*)sm;               // 32 KB
    int* keys1 = (int*)(sm + 32768);     // 32 KB
    int* C     = (int*)(sm + 65536);     // 64 KB (L / F / hd)
    int* P     = (int*)(sm + 131072);    //  8 KB (scan + scalars)
    int t = threadIdx.x;

    // ---- phase 0: masked-edge compaction (8 edges/thread) ----
    int cnt = 0;
#pragma unroll
    for (int j = 0; j < 8; ++j) {
        int e = t * 8 + j;
        cnt += (sim[e] >= SIM_TH) ? 1 : 0;
    }
    P[t] = cnt;
    __syncthreads();
    for (int off = 1; off < 1024; off <<= 1) {
        int mine  = P[t];
        int other = (t >= off) ? P[t - off] : 0;
        __syncthreads();
        P[t] = mine + other;
        __syncthreads();
    }
    int pos = P[t] - cnt;
    if (t == 1023) {
        int nn = P[1023];
        *nmask  = nn;
        P[1501] = nn;
        for (int j = 0; j < 4; ++j) rec[nn + j] = make_int4(0, 0, 0, 0);
    }
#pragma unroll
    for (int j = 0; j < 8; ++j) {
        int e = t * 8 + j;
        if (sim[e] >= SIM_TH) {
            int4 r;
            r.x = fo[x_idx[e]];
            r.y = fo[y_idx[e]];
            r.z = e;
            r.w = 0;
            rec[pos++] = r;
        }
    }
    __syncthreads();
    const int n = P[1501];

    // ---- phase 1: CC labels (min-label fixpoint) ----
    int* L = C;
    for (int c = t; c < NSLOTS; c += 1024) L[c] = c;
    __syncthreads();
    for (;;) {
        if (t == 0) P[1500] = 0;
        __syncthreads();
        for (int e = t; e < n; e += 1024) {
            int4 r = rec[e];
            int a = L[r.x], b = L[r.y];
            if (a < b)      { atomicMin(&L[r.y], a); P[1500] = 1; }
            else if (b < a) { atomicMin(&L[r.x], b); P[1500] = 1; }
        }
        __syncthreads();
        if (!P[1500]) break;
        __syncthreads();
        for (int c = t; c < NSLOTS; c += 1024) {
            int q  = L[c];
            int qq = L[q];
            if (qq < q) L[c] = qq;
        }
        __syncthreads();
    }
    __syncthreads();
    for (int e = t; e < n; e += 1024) keys0[e] = L[rec[e].x];
    __syncthreads();

    // ---- phase 2: stable LSD radix sort by label (4 x 4 bits) ----
    int* F = C;
    const int c8 = (n + 1023) >> 10;
    for (int pass = 0; pass < 4; ++pass) {
        int sh = pass * 4;
        const int*  kin  = (pass & 1) ? keys1 : keys0;
        int*        kout = (pass & 1) ? keys0 : keys1;
        const int4* in   = (pass & 1) ? srec : rec;
        int4*       out  = (pass & 1) ? rec : srec;
#pragma unroll
        for (int q = 0; q < 16; ++q) F[t * 16 + q] = 0;
        __syncthreads();
        for (int j = 0; j < c8; ++j) {
            int i = t * c8 + j;
            if (i < n) {
                int d = (kin[i] >> sh) & 15;
                F[d * 1024 + t] += 1;
            }
        }
        __syncthreads();
        int base = t * 16;
        int loc[16]; int s = 0;
#pragma unroll
        for (int q = 0; q < 16; ++q) { loc[q] = s; s += F[base + q]; }
        P[t] = s;
        __syncthreads();
        for (int off = 1; off < 1024; off <<= 1) {
            int mine  = P[t];
            int other = (t >= off) ? P[t - off] : 0;
            __syncthreads();
            P[t] = mine + other;
            __syncthreads();
        }
        int pre = (t == 0) ? 0 : P[t - 1];
#pragma unroll
        for (int q = 0; q < 16; ++q) F[base + q] = pre + loc[q];
        __syncthreads();
        for (int j = 0; j < c8; ++j) {
            int i = t * c8 + j;
            if (i < n) {
                int k = kin[i];
                int d = (k >> sh) & 15;
                int pp = F[d * 1024 + t]++;
                out[pp]  = in[i];
                kout[pp] = k;
            }
        }
        __syncthreads();
    }
    // after 4 passes sorted records are back in rec, keys in keys0

    // ---- phase 3: component boundaries ----
    unsigned char* hd = (unsigned char*)C;
    for (int i = t; i < n; i += 1024) {
        int l  = keys0[i];
        int lp = (i == 0) ? -1 : keys0[i - 1];
        hd[i] = (l != lp) ? 1 : 0;
    }
    __syncthreads();
    int hsum = 0;
    for (int j = 0; j < c8; ++j) {
        int i = t * c8 + j;
        if (i < n) hsum += hd[i];
    }
    P[t] = hsum;
    __syncthreads();
    for (int off = 1; off < 1024; off <<= 1) {
        int mine  = P[t];
        int other = (t >= off) ? P[t - off] : 0;
        __syncthreads();
        P[t] = mine + other;
        __syncthreads();
    }
    int run = P[t] - hsum;
    for (int j = 0; j < c8; ++j) {
        int i = t * c8 + j;
        if (i < n && hd[i]) { compStart[run] = i; ++run; }
    }
    if (t == 1023) { int total = P[1023]; *ncompOut = total; compStart[total] = n; }
}

// ---------------------------------------------------------------------------
// Kernel 6a: gate MLP split kernel — grid (512, 2).  Block (bx, h) computes
//   partial dot products for 16 edges over K-half h (h=0: x feats, h=1: y).
//   Measured 130 us, 0 bank conflicts (R17).  Partials -> pbuf[e][h][128].
// ---------------------------------------------------------------------------
__global__ __launch_bounds__(256) void gate_split_kernel(
        const float* __restrict__ xf, const float* __restrict__ yf,
        const float* __restrict__ W1,
        const int4* __restrict__ rec, const int* __restrict__ nmask,
        float* __restrict__ pbuf) {
    __shared__ float As[2][GBM][32];       //  4 KB
    __shared__ float Bs[2][H_DIM][33];     // 33.8 KB (pitch 33)
    __shared__ int   elds[GBM];

    int n  = *nmask;
    int b0 = blockIdx.x * GBM;
    if (b0 >= n) return;
    const int h = blockIdx.y;

    int t = threadIdx.x;
    if (t < GBM) {
        int idx = b0 + t;
        elds[t] = (idx < n) ? rec[idx].z : rec[b0].z;
    }
    __syncthreads();

    const int  arow = t >> 3;
    const int  acol = (t & 7) * 4;
    const bool aact = (t < 128);
    const int  brow = t >> 3;
    const int  bcol = (t & 7) * 4;

    const float* feat = h ? yf : xf;
    const float* arp  = feat + (size_t)elds[aact ? arow : 0] * D_FEAT + acol;
    const size_t koff = (size_t)h * D_FEAT;
    const float* w1p0 = W1 + (size_t)(brow +  0) * K2 + koff + bcol;
    const float* w1p1 = W1 + (size_t)(brow + 32) * K2 + koff + bcol;
    const float* w1p2 = W1 + (size_t)(brow + 64) * K2 + koff + bcol;
    const float* w1p3 = W1 + (size_t)(brow + 96) * K2 + koff + bcol;

    float4 aR = make_float4(0.f, 0.f, 0.f, 0.f);
    float4 bR0, bR1, bR2, bR3;

    if (aact) aR = *(const float4*)(arp + 0);
    bR0 = *(const float4*)(w1p0 + 0);
    bR1 = *(const float4*)(w1p1 + 0);
    bR2 = *(const float4*)(w1p2 + 0);
    bR3 = *(const float4*)(w1p3 + 0);
    if (aact) *(float4*)(&As[0][arow][acol]) = aR;
    Bs[0][brow +  0][bcol + 0] = bR0.x; Bs[0][brow +  0][bcol + 1] = bR0.y;
    Bs[0][brow +  0][bcol + 2] = bR0.z; Bs[0][brow +  0][bcol + 3] = bR0.w;
    Bs[0][brow + 32][bcol + 0] = bR1.x; Bs[0][brow + 32][bcol + 1] = bR1.y;
    Bs[0][brow + 32][bcol + 2] = bR1.z; Bs[0][brow + 32][bcol + 3] = bR1.w;
    Bs[0][brow + 64][bcol + 0] = bR2.x; Bs[0][brow + 64][bcol + 1] = bR2.y;
    Bs[0][brow + 64][bcol + 2] = bR2.z; Bs[0][brow + 64][bcol + 3] = bR2.w;
    Bs[0][brow + 96][bcol + 0] = bR3.x; Bs[0][brow + 96][bcol + 1] = bR3.y;
    Bs[0][brow + 96][bcol + 2] = bR3.z; Bs[0][brow + 96][bcol + 3] = bR3.w;
    __syncthreads();

    const int eb = (t >> 6) * 4;
    const int ln = t & 63;
    float acc[4][2] = {{0.f,0.f},{0.f,0.f},{0.f,0.f},{0.f,0.f}};

    const int NT = D_FEAT / 32;          // 64 tiles (one K-half)
    for (int tile = 0; tile < NT; ++tile) {
        const int buf = tile & 1;
        if (tile + 1 < NT) {
            int k0 = (tile + 1) * 32;
            if (aact) aR = *(const float4*)(arp + k0);
            bR0 = *(const float4*)(w1p0 + k0);
            bR1 = *(const float4*)(w1p1 + k0);
            bR2 = *(const float4*)(w1p2 + k0);
            bR3 = *(const float4*)(w1p3 + k0);
        }
#pragma unroll
        for (int kk = 0; kk < 32; kk += 4) {
            float4 a0 = *(const float4*)(&As[buf][eb + 0][kk]);
            float4 a1 = *(const float4*)(&As[buf][eb + 1][kk]);
            float4 a2 = *(const float4*)(&As[buf][eb + 2][kk]);
            float4 a3 = *(const float4*)(&As[buf][eb + 3][kk]);
            float bl0 = Bs[buf][ln][kk + 0];
            float bl1 = Bs[buf][ln][kk + 1];
            float bl2 = Bs[buf][ln][kk + 2];
            float bl3 = Bs[buf][ln][kk + 3];
            float bh0 = Bs[buf][ln + 64][kk + 0];
            float bh1 = Bs[buf][ln + 64][kk + 1];
            float bh2 = Bs[buf][ln + 64][kk + 2];
            float bh3 = Bs[buf][ln + 64][kk + 3];
            acc[0][0] = fmaf(a0.x, bl0, acc[0][0]);
            acc[0][0] = fmaf(a0.y, bl1, acc[0][0]);
            acc[0][0] = fmaf(a0.z, bl2, acc[0][0]);
            acc[0][0] = fmaf(a0.w, bl3, acc[0][0]);
            acc[0][1] = fmaf(a0.x, bh0, acc[0][1]);
            acc[0][1] = fmaf(a0.y, bh1, acc[0][1]);
            acc[0][1] = fmaf(a0.z, bh2, acc[0][1]);
            acc[0][1] = fmaf(a0.w, bh3, acc[0][1]);
            acc[1][0] = fmaf(a1.x, bl0, acc[1][0]);
            acc[1][0] = fmaf(a1.y, bl1, acc[1][0]);
            acc[1][0] = fmaf(a1.z, bl2, acc[1][0]);
            acc[1][0] = fmaf(a1.w, bl3, acc[1][0]);
            acc[1][1] = fmaf(a1.x, bh0, acc[1][1]);
            acc[1][1] = fmaf(a1.y, bh1, acc[1][1]);
            acc[1][1] = fmaf(a1.z, bh2, acc[1][1]);
            acc[1][1] = fmaf(a1.w, bh3, acc[1][1]);
            acc[2][0] = fmaf(a2.x, bl0, acc[2][0]);
            acc[2][0] = fmaf(a2.y, bl1, acc[2][0]);
            acc[2][0] = fmaf(a2.z, bl2, acc[2][0]);
            acc[2][0] = fmaf(a2.w, bl3, acc[2][0]);
            acc[2][1] = fmaf(a2.x, bh0, acc[2][1]);
            acc[2][1] = fmaf(a2.y, bh1, acc[2][1]);
            acc[2][1] = fmaf(a2.z, bh2, acc[2][1]);
            acc[2][1] = fmaf(a2.w, bh3, acc[2][1]);
            acc[3][0] = fmaf(a3.x, bl0, acc[3][0]);
            acc[3][0] = fmaf(a3.y, bl1, acc[3][0]);
            acc[3][0] = fmaf(a3.z, bl2, acc[3][0]);
            acc[3][0] = fmaf(a3.w, bl3, acc[3][0]);
            acc[3][1] = fmaf(a3.x, bh0, acc[3][1]);
            acc[3][1] = fmaf(a3.y, bh1, acc[3][1]);
            acc[3][1] = fmaf(a3.z, bh2, acc[3][1]);
            acc[3][1] = fmaf(a3.w, bh3, acc[3][1]);
        }
        if (tile + 1 < NT) {
            const int nb = buf ^ 1;
            if (aact) *(float4*)(&As[nb][arow][acol]) = aR;
            Bs[nb][brow +  0][bcol + 0] = bR0.x; Bs[nb][brow +  0][bcol + 1] = bR0.y;
            Bs[nb][brow +  0][bcol + 2] = bR0.z; Bs[nb][brow +  0][bcol + 3] = bR0.w;
            Bs[nb][brow + 32][bcol + 0] = bR1.x; Bs[nb][brow + 32][bcol + 1] = bR1.y;
            Bs[nb][brow + 32][bcol + 2] = bR1.z; Bs[nb][brow + 32][bcol + 3] = bR1.w;
            Bs[nb][brow + 64][bcol + 0] = bR2.x; Bs[nb][brow + 64][bcol + 1] = bR2.y;
            Bs[nb][brow + 64][bcol + 2] = bR2.z; Bs[nb][brow + 64][bcol + 3] = bR2.w;
            Bs[nb][brow + 96][bcol + 0] = bR3.x; Bs[nb][brow + 96][bcol + 1] = bR3.y;
            Bs[nb][brow + 96][bcol + 2] = bR3.z; Bs[nb][brow + 96][bcol + 3] = bR3.w;
        }
        __syncthreads();
    }

#pragma unroll
    for (int j = 0; j < 4; ++j) {
        float* pb = pbuf + (((size_t)(b0 + eb + j) * 2 + h) << 7);
        pb[ln]      = acc[j][0];
        pb[ln + 64] = acc[j][1];
    }
}

// ---------------------------------------------------------------------------
// Kernel 6b: gate epilogue — h = relu(p0+p1+b1) (R12's verified combine
//   order), then the exact legacy W2 chain, sigmoid; fills w_out and rec.w.
// ---------------------------------------------------------------------------
__global__ __launch_bounds__(256) void gate_fin_kernel(
        const float* __restrict__ pbuf, const float* __restrict__ b1,
        const float* __restrict__ W2, const float* __restrict__ b2,
        int4* __restrict__ rec, const int* __restrict__ nmask,
        float* __restrict__ wout) {
    int e = blockIdx.x * blockDim.x + threadIdx.x;
    if (e >= *nmask) return;
    const float* p0 = pbuf + ((size_t)e << 8);
    const float* p1 = p0 + 128;
    float s = 0.f;
    for (int c = 0; c < 32; ++c) {
        float p = 0.f;
#pragma unroll
        for (int q = 0; q < 4; ++q) {
            int nn = 4 * c + q;
            float hh = fmaxf(p0[nn] + p1[nn] + b1[nn], 0.f);
            p = fmaf(hh, W2[nn], p);
        }
        s += p;
    }
    float logit = s + b2[0];
    float attn  = 1.f / (1.f + expf(-logit));
    wout[rec[e].z] = attn;
    ((int*)&rec[e])[3] = __float_as_int(attn);
}

// ---------------------------------------------------------------------------
// Kernel 6-fallback: gate MLP v3 single-kernel (measured 160 us) — used when
//   ws_size is too small for the 4.2 MB partial buffer.
// ---------------------------------------------------------------------------
__global__ __launch_bounds__(256) void gate_v3_kernel(
        const float* __restrict__ xf, const float* __restrict__ yf,
        const float* __restrict__ W1, const float* __restrict__ b1,
        const float* __restrict__ W2, const float* __restrict__ b2,
        int4* __restrict__ rec, const int* __restrict__ nmask,
        float* __restrict__ wout) {
    __shared__ float As[2][GBM][32];
    __shared__ float Bs[2][H_DIM][33];
    __shared__ float hbuf[GBM][132];
    __shared__ int   elds[GBM];

    int n  = *nmask;
    int b0 = blockIdx.x * GBM;
    if (b0 >= n) return;

    int t = threadIdx.x;
    if (t < GBM) {
        int idx = b0 + t;
        elds[t] = (idx < n) ? rec[idx].z : rec[b0].z;
    }
    __syncthreads();

    const int  arow = t >> 3;
    const int  acol = (t & 7) * 4;
    const bool aact = (t < 128);
    const int  brow = t >> 3;
    const int  bcol = (t & 7) * 4;

    const float* xrow = xf + (size_t)elds[aact ? arow : 0] * D_FEAT + acol;
    const float* yrow = yf + (size_t)elds[aact ? arow : 0] * D_FEAT + acol;
    const float* w1p0 = W1 + (size_t)(brow +  0) * K2 + bcol;
    const float* w1p1 = W1 + (size_t)(brow + 32) * K2 + bcol;
    const float* w1p2 = W1 + (size_t)(brow + 64) * K2 + bcol;
    const float* w1p3 = W1 + (size_t)(brow + 96) * K2 + bcol;

    float4 aR = make_float4(0.f, 0.f, 0.f, 0.f);
    float4 bR0, bR1, bR2, bR3;

    if (aact) aR = *(const float4*)(xrow + 0);
    bR0 = *(const float4*)(w1p0 + 0);
    bR1 = *(const float4*)(w1p1 + 0);
    bR2 = *(const float4*)(w1p2 + 0);
    bR3 = *(const float4*)(w1p3 + 0);
    if (aact) *(float4*)(&As[0][arow][acol]) = aR;
    Bs[0][brow +  0][bcol + 0] = bR0.x; Bs[0][brow +  0][bcol + 1] = bR0.y;
    Bs[0][brow +  0][bcol + 2] = bR0.z; Bs[0][brow +  0][bcol + 3] = bR0.w;
    Bs[0][brow + 32][bcol + 0] = bR1.x; Bs[0][brow + 32][bcol + 1] = bR1.y;
    Bs[0][brow + 32][bcol + 2] = bR1.z; Bs[0][brow + 32][bcol + 3] = bR1.w;
    Bs[0][brow + 64][bcol + 0] = bR2.x; Bs[0][brow + 64][bcol + 1] = bR2.y;
    Bs[0][brow + 64][bcol + 2] = bR2.z; Bs[0][brow + 64][bcol + 3] = bR2.w;
    Bs[0][brow + 96][bcol + 0] = bR3.x; Bs[0][brow + 96][bcol + 1] = bR3.y;
    Bs[0][brow + 96][bcol + 2] = bR3.z; Bs[0][brow + 96][bcol + 3] = bR3.w;
    __syncthreads();

    const int eb = (t >> 6) * 4;
    const int ln = t & 63;
    float acc[4][2] = {{0.f,0.f},{0.f,0.f},{0.f,0.f},{0.f,0.f}};

    const int NT = K2 / 32;
    for (int tile = 0; tile < NT; ++tile) {
        const int buf = tile & 1;
        if (tile + 1 < NT) {
            int k0 = (tile + 1) * 32;
            if (aact) {
                const float* ap = (k0 < D_FEAT) ? (xrow + k0) : (yrow + (k0 - D_FEAT));
                aR = *(const float4*)ap;
            }
            bR0 = *(const float4*)(w1p0 + k0);
            bR1 = *(const float4*)(w1p1 + k0);
            bR2 = *(const float4*)(w1p2 + k0);
            bR3 = *(const float4*)(w1p3 + k0);
        }
#pragma unroll
        for (int kk = 0; kk < 32; kk += 4) {
            float4 a0 = *(const float4*)(&As[buf][eb + 0][kk]);
            float4 a1 = *(const float4*)(&As[buf][eb + 1][kk]);
            float4 a2 = *(const float4*)(&As[buf][eb + 2][kk]);
            float4 a3 = *(const float4*)(&As[buf][eb + 3][kk]);
            float bl0 = Bs[buf][ln][kk + 0];
            float bl1 = Bs[buf][ln][kk + 1];
            float bl2 = Bs[buf][ln][kk + 2];
            float bl3 = Bs[buf][ln][kk + 3];
            float bh0 = Bs[buf][ln + 64][kk + 0];
            float bh1 = Bs[buf][ln + 64][kk + 1];
            float bh2 = Bs[buf][ln + 64][kk + 2];
            float bh3 = Bs[buf][ln + 64][kk + 3];
            acc[0][0] = fmaf(a0.x, bl0, acc[0][0]);
            acc[0][0] = fmaf(a0.y, bl1, acc[0][0]);
            acc[0][0] = fmaf(a0.z, bl2, acc[0][0]);
            acc[0][0] = fmaf(a0.w, bl3, acc[0][0]);
            acc[0][1] = fmaf(a0.x, bh0, acc[0][1]);
            acc[0][1] = fmaf(a0.y, bh1, acc[0][1]);
            acc[0][1] = fmaf(a0.z, bh2, acc[0][1]);
            acc[0][1] = fmaf(a0.w, bh3, acc[0][1]);
            acc[1][0] = fmaf(a1.x, bl0, acc[1][0]);
            acc[1][0] = fmaf(a1.y, bl1, acc[1][0]);
            acc[1][0] = fmaf(a1.z, bl2, acc[1][0]);
            acc[1][0] = fmaf(a1.w, bl3, acc[1][0]);
            acc[1][1] = fmaf(a1.x, bh0, acc[1][1]);
            acc[1][1] = fmaf(a1.y, bh1, acc[1][1]);
            acc[1][1] = fmaf(a1.z, bh2, acc[1][1]);
            acc[1][1] = fmaf(a1.w, bh3, acc[1][1]);
            acc[2][0] = fmaf(a2.x, bl0, acc[2][0]);
            acc[2][0] = fmaf(a2.y, bl1, acc[2][0]);
            acc[2][0] = fmaf(a2.z, bl2, acc[2][0]);
            acc[2][0] = fmaf(a2.w, bl3, acc[2][0]);
            acc[2][1] = fmaf(a2.x, bh0, acc[2][1]);
            acc[2][1] = fmaf(a2.y, bh1, acc[2][1]);
            acc[2][1] = fmaf(a2.z, bh2, acc[2][1]);
            acc[2][1] = fmaf(a2.w, bh3, acc[2][1]);
            acc[3][0] = fmaf(a3.x, bl0, acc[3][0]);
            acc[3][0] = fmaf(a3.y, bl1, acc[3][0]);
            acc[3][0] = fmaf(a3.z, bl2, acc[3][0]);
            acc[3][0] = fmaf(a3.w, bl3, acc[3][0]);
            acc[3][1] = fmaf(a3.x, bh0, acc[3][1]);
            acc[3][1] = fmaf(a3.y, bh1, acc[3][1]);
            acc[3][1] = fmaf(a3.z, bh2, acc[3][1]);
            acc[3][1] = fmaf(a3.w, bh3, acc[3][1]);
        }
        if (tile + 1 < NT) {
            const int nb = buf ^ 1;
            if (aact) *(float4*)(&As[nb][arow][acol]) = aR;
            Bs[nb][brow +  0][bcol + 0] = bR0.x; Bs[nb][brow +  0][bcol + 1] = bR0.y;
            Bs[nb][brow +  0][bcol + 2] = bR0.z; Bs[nb][brow +  0][bcol + 3] = bR0.w;
            Bs[nb][brow + 32][bcol + 0] = bR1.x; Bs[nb][brow + 32][bcol + 1] = bR1.y;
            Bs[nb][brow + 32][bcol + 2] = bR1.z; Bs[nb][brow + 32][bcol + 3] = bR1.w;
            Bs[nb][brow + 64][bcol + 0] = bR2.x; Bs[nb][brow + 64][bcol + 1] = bR2.y;
            Bs[nb][brow + 64][bcol + 2] = bR2.z; Bs[nb][brow + 64][bcol + 3] = bR2.w;
            Bs[nb][brow + 96][bcol + 0] = bR3.x; Bs[nb][brow + 96][bcol + 1] = bR3.y;
            Bs[nb][brow + 96][bcol + 2] = bR3.z; Bs[nb][brow + 96][bcol + 3] = bR3.w;
        }
        __syncthreads();
    }

#pragma unroll
    for (int j = 0; j < 4; ++j) {
        hbuf[eb + j][ln]      = fmaxf(acc[j][0] + b1[ln], 0.f);
        hbuf[eb + j][ln + 64] = fmaxf(acc[j][1] + b1[ln + 64], 0.f);
    }
    __syncthreads();
    if (t < GBM && b0 + t < n) {
        float s = 0.f;
        for (int c = 0; c < 32; ++c) {
            float p = 0.f;
#pragma unroll
            for (int q = 0; q < 4; ++q)
                p = fmaf(hbuf[t][4 * c + q], W2[4 * c + q], p);
            s += p;
        }
        float logit = s + b2[0];
        float attn  = 1.f / (1.f + expf(-logit));
        wout[elds[t]] = attn;
        ((int*)&rec[b0 + t])[3] = __float_as_int(attn);
    }
}

// ---------------------------------------------------------------------------
// Kernel 9: exact union-find, parallel over connected components.
// ---------------------------------------------------------------------------
__global__ __launch_bounds__(1024) void uf_kernel(
        const int4* __restrict__ srec, const int* __restrict__ ncompPtr,
        const int* __restrict__ compStart,
        const int* __restrict__ orig, const float* __restrict__ rin,
        int* __restrict__ gpar, float* __restrict__ grank) {
    extern __shared__ char smem[];
    int2* nd = (int2*)smem;    // 128 KB {parent, rank-bits}
    int* ndw = (int*)smem;
    int t = threadIdx.x;
    for (int c = t; c < NSLOTS; c += 1024) {
        int o = orig[c];
        float r = (o >= 0) ? rin[o] : 1.0f;
        nd[c] = make_int2(c, __float_as_int(r));
    }
    __syncthreads();

    int ncomp = *ncompPtr;
    for (int c = t; c < ncomp; c += 1024) {
        int s  = compStart[c];
        int en = compStart[c + 1];
        for (int j = s; j < en; ++j) {
            int4 r = srec[j];
            int x = r.x, y = r.y;
            float wi = __int_as_float(r.w);
            int p;
            int rx = x;
            while ((p = ndw[rx * 2]) != rx) rx = p;
            int j2 = x;
            while ((p = ndw[j2 * 2]) != rx) { ndw[j2 * 2] = rx; j2 = p; }
            int ry = y;
            while ((p = ndw[ry * 2]) != ry) ry = p;
            j2 = y;
            while ((p = ndw[j2 * 2]) != ry) { ndw[j2 * 2] = ry; j2 = p; }
            if (rx != ry) {
                float ka = __int_as_float(ndw[rx * 2 + 1]);
                float kb = __int_as_float(ndw[ry * 2 + 1]);
                bool bx = ka > kb;
                int big = bx ? rx : ry, small = bx ? ry : rx;
                float nr = bx ? (ka + kb * wi) : (kb + ka * wi);
                ndw[small * 2]   = big;
                ndw[big * 2 + 1] = __float_as_int(nr);
            }
        }
    }
    __syncthreads();
    for (int c = t; c < NSLOTS; c += 1024) {
        int2 v = nd[c];
        gpar[c] = v.x;
        grank[c] = __int_as_float(v.y);
    }
}

// ---------------------------------------------------------------------------
// Kernel 10: finalize — per node, claimed -> compact result, else input copy.
// ---------------------------------------------------------------------------
__global__ void finalize_kernel(const int* __restrict__ pin, const float* __restrict__ rin,
                                const int* __restrict__ fo, const int* __restrict__ orig,
                                const int* __restrict__ gpar, const float* __restrict__ grank,
                                float* __restrict__ pout, float* __restrict__ rout) {
    int i = blockIdx.x * blockDim.x + threadIdx.x;
    if (i >= N_NODES) return;
    int c = fo[i];
    float pv, rv;
    if (c != 0x7FFFFFFF) {
        pv = (float)orig[gpar[c]];
        rv = grank[c];
    } else {
        pv = (float)pin[i];
        rv = rin[i];
    }
    pout[i] = pv;
    rout[i] = rv;
}

// ---------------------------------------------------------------------------
extern "C" void kernel_launch(void* const* d_in, const int* in_sizes, int n_in,
                              void* d_out, int out_size, void* d_ws, size_t ws_size,
                              hipStream_t stream) {
    const int*   x_idx = (const int*)d_in[0];
    const int*   y_idx = (const int*)d_in[1];
    const float* xf    = (const float*)d_in[2];
    const float* yf    = (const float*)d_in[3];
    const float* W1    = (const float*)d_in[4];
    const float* b1    = (const float*)d_in[5];
    const float* W2    = (const float*)d_in[6];
    const float* b2    = (const float*)d_in[7];
    const int*   pin   = (const int*)d_in[8];
    const float* rin   = (const float*)d_in[9];

    float* out   = (float*)d_out;
    float* w_out = out;                        // [E]
    float* pout  = out + E_EDGES;              // [N]
    float* rout  = out + E_EDGES + N_NODES;    // [N]

    char* ws = (char*)d_ws;
    float* sim_ws  = (float*)(ws + 0);         //  32768 B
    int*   fo      = (int*)  (ws + 32768);     // 400000 B
    int*   orig    = (int*)  (ws + 432768);    //  65536 B
    int4*  rec     = (int4*) (ws + 498304);    // 131136 B  (8192+4 recs)
    int*   nmask   = (int*)  (ws + 629440);    //     64 B
    int*   gpar    = (int*)  (ws + 629504);    //  65536 B
    float* grank   = (float*)(ws + 695040);    //  65536 B
    int4*  srec    = (int4*) (ws + 760576);    // 131072 B (radix scratch)
    int*   compSt  = (int*)  (ws + 891648);    //  32772 B (8193 ints)
    int*   ncomp   = (int*)  (ws + 924424);    //      4 B
    float* pbuf    = (float*)(ws + 924480);    // 4.2 MB partials (if ws allows)

    const size_t need2 = 924480 + (size_t)E_EDGES * 2 * 128 * sizeof(float);

    // 1) cosine sim
    sim_kernel<<<(E_EDGES * 64) / 256, 256, 0, stream>>>(xf, yf, sim_ws);
    // 2) compact-id mapping + zero w
    int g = (N_NODES + 255) / 256;
    initmap_kernel<<<g, 256, 0, stream>>>(fo, orig, w_out);
    claim_kernel<<<NSLOTS / 256, 256, 0, stream>>>(x_idx, y_idx, fo);
    orig_kernel<<<NSLOTS / 256, 256, 0, stream>>>(x_idx, y_idx, fo, orig);
    // 3) merged maskscan + CC-label + radix sort + boundaries (one block)
    sortprep_kernel<<<1, 1024, 139264, stream>>>(x_idx, y_idx, fo, sim_ws,
                                                 rec, srec, nmask, compSt, ncomp);
    // 4) gate MLP over masked (sorted) edges — K-split x2 or fallback
    if (ws_size >= need2) {
        dim3 gg(E_EDGES / GBM, 2);
        gate_split_kernel<<<gg, 256, 0, stream>>>(xf, yf, W1, rec, nmask, pbuf);
        gate_fin_kernel<<<E_EDGES / 256, 256, 0, stream>>>(pbuf, b1, W2, b2,
                                                           rec, nmask, w_out);
    } else {
        gate_v3_kernel<<<E_EDGES / GBM, 256, 0, stream>>>(xf, yf, W1, b1, W2, b2,
                                                          rec, nmask, w_out);
    }
    // 5) exact UF, parallel over components (LDS 128 KB); sorted edges in rec
    uf_kernel<<<1, 1024, 131072, stream>>>(rec, ncomp, compSt, orig, rin, gpar, grank);
    // 6) finalize outputs (base copy + compact scatter fused)
    finalize_kernel<<<g, 256, 0, stream>>>(pin, rin, fo, orig, gpar, grank, pout, rout);
}

// Round 21
// 267.555 us; speedup vs baseline: 1.1812x; 1.0259x over previous
//
#include <hip/hip_runtime.h>
#include <math.h>

#define E_EDGES 8192
#define D_FEAT 2048
#define K2 4096   // 2*D
#define H_DIM 128
#define N_NODES 100000
#define SIM_TH 0.7f
#define NSLOTS (2 * E_EDGES)   // 16384 compact slots
#define GBM 16                 // gate edges per block

// ---------------------------------------------------------------------------
// Kernel 1: cosine similarity per edge (one wave per edge) + fused init of
//   fo (=INT_MAX), orig (=-1), wout (=0).  Grid 2048x256 covers all ranges;
//   init stores are independent of sim math; claim runs after (stream order).
// ---------------------------------------------------------------------------
__global__ __launch_bounds__(256) void sim_kernel(const float* __restrict__ xf,
                                                  const float* __restrict__ yf,
                                                  float* __restrict__ sim,
                                                  int* __restrict__ fo,
                                                  int* __restrict__ orig,
                                                  float* __restrict__ wout) {
    int gid  = blockIdx.x * blockDim.x + threadIdx.x;
    if (gid < N_NODES) fo[gid] = 0x7FFFFFFF;
    if (gid < NSLOTS)  orig[gid] = -1;
    if (gid < E_EDGES) wout[gid] = 0.f;

    int wave = gid >> 6;
    int lane = threadIdx.x & 63;
    if (wave >= E_EDGES) return;
    const float4* xp = (const float4*)(xf + (size_t)wave * D_FEAT);
    const float4* yp = (const float4*)(yf + (size_t)wave * D_FEAT);
    float dot = 0.f, xx = 0.f, yy = 0.f;
#pragma unroll
    for (int j = 0; j < 8; ++j) {
        float4 a = xp[lane + j * 64];
        float4 b = yp[lane + j * 64];
        dot += a.x * b.x + a.y * b.y + a.z * b.z + a.w * b.w;
        xx  += a.x * a.x + a.y * a.y + a.z * a.z + a.w * a.w;
        yy  += b.x * b.x + b.y * b.y + b.z * b.z + b.w * b.w;
    }
#pragma unroll
    for (int off = 32; off; off >>= 1) {
        dot += __shfl_xor(dot, off);
        xx  += __shfl_xor(xx, off);
        yy  += __shfl_xor(yy, off);
    }
    if (lane == 0) {
        float nx = fmaxf(sqrtf(xx), 1e-8f);
        float ny = fmaxf(sqrtf(yy), 1e-8f);
        sim[wave] = dot / (nx * ny);
    }
}

// ---------------------------------------------------------------------------
// Kernel 3: claim compact slot = first occurrence index in x0,y0,x1,y1,...
// ---------------------------------------------------------------------------
__global__ void claim_kernel(const int* __restrict__ x_idx, const int* __restrict__ y_idx,
                             int* __restrict__ fo) {
    int i = blockIdx.x * blockDim.x + threadIdx.x;
    if (i >= NSLOTS) return;
    int e = i >> 1;
    int v = (i & 1) ? y_idx[e] : x_idx[e];
    atomicMin(&fo[v], i);
}

// ---------------------------------------------------------------------------
// Kernel 4: orig[slot] = node for claimed slots.
// ---------------------------------------------------------------------------
__global__ void orig_kernel(const int* __restrict__ x_idx, const int* __restrict__ y_idx,
                            const int* __restrict__ fo, int* __restrict__ orig) {
    int i = blockIdx.x * blockDim.x + threadIdx.x;
    if (i >= NSLOTS) return;
    int e = i >> 1;
    int v = (i & 1) ? y_idx[e] : x_idx[e];
    if (fo[v] == i) orig[i] = v;
}

// ---------------------------------------------------------------------------
// Kernel 5: order-preserving compaction of masked edges into records
//           rec = {cx, cy, eidx, (w filled later by gate)} + 4 zero pads.
// ---------------------------------------------------------------------------
__global__ __launch_bounds__(256) void maskscan_kernel(
        const int* __restrict__ x_idx, const int* __restrict__ y_idx,
        const int* __restrict__ fo, const float* __restrict__ sim,
        int4* __restrict__ rec, int* __restrict__ nmask) {
    __shared__ int partial[256];
    int t = threadIdx.x;
    int cnt = 0;
    for (int j = 0; j < 32; ++j) {
        int e = t * 32 + j;
        cnt += (sim[e] >= SIM_TH) ? 1 : 0;
    }
    partial[t] = cnt;
    __syncthreads();
    for (int off = 1; off < 256; off <<= 1) {
        int mine  = partial[t];
        int other = (t >= off) ? partial[t - off] : 0;
        __syncthreads();
        partial[t] = mine + other;
        __syncthreads();
    }
    int pos = partial[t] - cnt;
    if (t == 255) {
        int nn = partial[255];
        *nmask = nn;
        for (int j = 0; j < 4; ++j) rec[nn + j] = make_int4(0, 0, 0, 0);
    }
    for (int j = 0; j < 32; ++j) {
        int e = t * 32 + j;
        if (sim[e] >= SIM_TH) {
            int4 r;
            r.x = fo[x_idx[e]];
            r.y = fo[y_idx[e]];
            r.z = e;
            r.w = 0;
            rec[pos++] = r;
        }
    }
}

// ---------------------------------------------------------------------------
// Kernel 6a: gate MLP split kernel — grid (512, 2).  Block (bx, h) computes
//   partial dot products for 16 edges over K-half h (h=0: x feats, h=1: y).
//   Measured 130 us, 0 bank conflicts (R17).  Partials -> pbuf[e][h][128].
// ---------------------------------------------------------------------------
__global__ __launch_bounds__(256) void gate_split_kernel(
        const float* __restrict__ xf, const float* __restrict__ yf,
        const float* __restrict__ W1,
        const int4* __restrict__ rec, const int* __restrict__ nmask,
        float* __restrict__ pbuf) {
    __shared__ float As[2][GBM][32];       //  4 KB
    __shared__ float Bs[2][H_DIM][33];     // 33.8 KB (pitch 33)
    __shared__ int   elds[GBM];

    int n  = *nmask;
    int b0 = blockIdx.x * GBM;
    if (b0 >= n) return;
    const int h = blockIdx.y;

    int t = threadIdx.x;
    if (t < GBM) {
        int idx = b0 + t;
        elds[t] = (idx < n) ? rec[idx].z : rec[b0].z;
    }
    __syncthreads();

    const int  arow = t >> 3;
    const int  acol = (t & 7) * 4;
    const bool aact = (t < 128);
    const int  brow = t >> 3;
    const int  bcol = (t & 7) * 4;

    const float* feat = h ? yf : xf;
    const float* arp  = feat + (size_t)elds[aact ? arow : 0] * D_FEAT + acol;
    const size_t koff = (size_t)h * D_FEAT;
    const float* w1p0 = W1 + (size_t)(brow +  0) * K2 + koff + bcol;
    const float* w1p1 = W1 + (size_t)(brow + 32) * K2 + koff + bcol;
    const float* w1p2 = W1 + (size_t)(brow + 64) * K2 + koff + bcol;
    const float* w1p3 = W1 + (size_t)(brow + 96) * K2 + koff + bcol;

    float4 aR = make_float4(0.f, 0.f, 0.f, 0.f);
    float4 bR0, bR1, bR2, bR3;

    if (aact) aR = *(const float4*)(arp + 0);
    bR0 = *(const float4*)(w1p0 + 0);
    bR1 = *(const float4*)(w1p1 + 0);
    bR2 = *(const float4*)(w1p2 + 0);
    bR3 = *(const float4*)(w1p3 + 0);
    if (aact) *(float4*)(&As[0][arow][acol]) = aR;
    Bs[0][brow +  0][bcol + 0] = bR0.x; Bs[0][brow +  0][bcol + 1] = bR0.y;
    Bs[0][brow +  0][bcol + 2] = bR0.z; Bs[0][brow +  0][bcol + 3] = bR0.w;
    Bs[0][brow + 32][bcol + 0] = bR1.x; Bs[0][brow + 32][bcol + 1] = bR1.y;
    Bs[0][brow + 32][bcol + 2] = bR1.z; Bs[0][brow + 32][bcol + 3] = bR1.w;
    Bs[0][brow + 64][bcol + 0] = bR2.x; Bs[0][brow + 64][bcol + 1] = bR2.y;
    Bs[0][brow + 64][bcol + 2] = bR2.z; Bs[0][brow + 64][bcol + 3] = bR2.w;
    Bs[0][brow + 96][bcol + 0] = bR3.x; Bs[0][brow + 96][bcol + 1] = bR3.y;
    Bs[0][brow + 96][bcol + 2] = bR3.z; Bs[0][brow + 96][bcol + 3] = bR3.w;
    __syncthreads();

    const int eb = (t >> 6) * 4;
    const int ln = t & 63;
    float acc[4][2] = {{0.f,0.f},{0.f,0.f},{0.f,0.f},{0.f,0.f}};

    const int NT = D_FEAT / 32;          // 64 tiles (one K-half)
    for (int tile = 0; tile < NT; ++tile) {
        const int buf = tile & 1;
        if (tile + 1 < NT) {
            int k0 = (tile + 1) * 32;
            if (aact) aR = *(const float4*)(arp + k0);
            bR0 = *(const float4*)(w1p0 + k0);
            bR1 = *(const float4*)(w1p1 + k0);
            bR2 = *(const float4*)(w1p2 + k0);
            bR3 = *(const float4*)(w1p3 + k0);
        }
#pragma unroll
        for (int kk = 0; kk < 32; kk += 4) {
            float4 a0 = *(const float4*)(&As[buf][eb + 0][kk]);
            float4 a1 = *(const float4*)(&As[buf][eb + 1][kk]);
            float4 a2 = *(const float4*)(&As[buf][eb + 2][kk]);
            float4 a3 = *(const float4*)(&As[buf][eb + 3][kk]);
            float bl0 = Bs[buf][ln][kk + 0];
            float bl1 = Bs[buf][ln][kk + 1];
            float bl2 = Bs[buf][ln][kk + 2];
            float bl3 = Bs[buf][ln][kk + 3];
            float bh0 = Bs[buf][ln + 64][kk + 0];
            float bh1 = Bs[buf][ln + 64][kk + 1];
            float bh2 = Bs[buf][ln + 64][kk + 2];
            float bh3 = Bs[buf][ln + 64][kk + 3];
            acc[0][0] = fmaf(a0.x, bl0, acc[0][0]);
            acc[0][0] = fmaf(a0.y, bl1, acc[0][0]);
            acc[0][0] = fmaf(a0.z, bl2, acc[0][0]);
            acc[0][0] = fmaf(a0.w, bl3, acc[0][0]);
            acc[0][1] = fmaf(a0.x, bh0, acc[0][1]);
            acc[0][1] = fmaf(a0.y, bh1, acc[0][1]);
            acc[0][1] = fmaf(a0.z, bh2, acc[0][1]);
            acc[0][1] = fmaf(a0.w, bh3, acc[0][1]);
            acc[1][0] = fmaf(a1.x, bl0, acc[1][0]);
            acc[1][0] = fmaf(a1.y, bl1, acc[1][0]);
            acc[1][0] = fmaf(a1.z, bl2, acc[1][0]);
            acc[1][0] = fmaf(a1.w, bl3, acc[1][0]);
            acc[1][1] = fmaf(a1.x, bh0, acc[1][1]);
            acc[1][1] = fmaf(a1.y, bh1, acc[1][1]);
            acc[1][1] = fmaf(a1.z, bh2, acc[1][1]);
            acc[1][1] = fmaf(a1.w, bh3, acc[1][1]);
            acc[2][0] = fmaf(a2.x, bl0, acc[2][0]);
            acc[2][0] = fmaf(a2.y, bl1, acc[2][0]);
            acc[2][0] = fmaf(a2.z, bl2, acc[2][0]);
            acc[2][0] = fmaf(a2.w, bl3, acc[2][0]);
            acc[2][1] = fmaf(a2.x, bh0, acc[2][1]);
            acc[2][1] = fmaf(a2.y, bh1, acc[2][1]);
            acc[2][1] = fmaf(a2.z, bh2, acc[2][1]);
            acc[2][1] = fmaf(a2.w, bh3, acc[2][1]);
            acc[3][0] = fmaf(a3.x, bl0, acc[3][0]);
            acc[3][0] = fmaf(a3.y, bl1, acc[3][0]);
            acc[3][0] = fmaf(a3.z, bl2, acc[3][0]);
            acc[3][0] = fmaf(a3.w, bl3, acc[3][0]);
            acc[3][1] = fmaf(a3.x, bh0, acc[3][1]);
            acc[3][1] = fmaf(a3.y, bh1, acc[3][1]);
            acc[3][1] = fmaf(a3.z, bh2, acc[3][1]);
            acc[3][1] = fmaf(a3.w, bh3, acc[3][1]);
        }
        if (tile + 1 < NT) {
            const int nb = buf ^ 1;
            if (aact) *(float4*)(&As[nb][arow][acol]) = aR;
            Bs[nb][brow +  0][bcol + 0] = bR0.x; Bs[nb][brow +  0][bcol + 1] = bR0.y;
            Bs[nb][brow +  0][bcol + 2] = bR0.z; Bs[nb][brow +  0][bcol + 3] = bR0.w;
            Bs[nb][brow + 32][bcol + 0] = bR1.x; Bs[nb][brow + 32][bcol + 1] = bR1.y;
            Bs[nb][brow + 32][bcol + 2] = bR1.z; Bs[nb][brow + 32][bcol + 3] = bR1.w;
            Bs[nb][brow + 64][bcol + 0] = bR2.x; Bs[nb][brow + 64][bcol + 1] = bR2.y;
            Bs[nb][brow + 64][bcol + 2] = bR2.z; Bs[nb][brow + 64][bcol + 3] = bR2.w;
            Bs[nb][brow + 96][bcol + 0] = bR3.x; Bs[nb][brow + 96][bcol + 1] = bR3.y;
            Bs[nb][brow + 96][bcol + 2] = bR3.z; Bs[nb][brow + 96][bcol + 3] = bR3.w;
        }
        __syncthreads();
    }

#pragma unroll
    for (int j = 0; j < 4; ++j) {
        float* pb = pbuf + (((size_t)(b0 + eb + j) * 2 + h) << 7);
        pb[ln]      = acc[j][0];
        pb[ln + 64] = acc[j][1];
    }
}

// ---------------------------------------------------------------------------
// Kernel 6b: gate epilogue — h = relu(p0+p1+b1), exact legacy W2 chain,
//   sigmoid; fills w_out and rec.w.
// ---------------------------------------------------------------------------
__global__ __launch_bounds__(256) void gate_fin_kernel(
        const float* __restrict__ pbuf, const float* __restrict__ b1,
        const float* __restrict__ W2, const float* __restrict__ b2,
        int4* __restrict__ rec, const int* __restrict__ nmask,
        float* __restrict__ wout) {
    int e = blockIdx.x * blockDim.x + threadIdx.x;
    if (e >= *nmask) return;
    const float* p0 = pbuf + ((size_t)e << 8);
    const float* p1 = p0 + 128;
    float s = 0.f;
    for (int c = 0; c < 32; ++c) {
        float p = 0.f;
#pragma unroll
        for (int q = 0; q < 4; ++q) {
            int nn = 4 * c + q;
            float hh = fmaxf(p0[nn] + p1[nn] + b1[nn], 0.f);
            p = fmaf(hh, W2[nn], p);
        }
        s += p;
    }
    float logit = s + b2[0];
    float attn  = 1.f / (1.f + expf(-logit));
    wout[rec[e].z] = attn;
    ((int*)&rec[e])[3] = __float_as_int(attn);
}

// ---------------------------------------------------------------------------
// Kernel 6-fallback: gate MLP v3 single-kernel (measured 160 us) — used when
//   ws_size is too small for the 4.2 MB partial buffer.
// ---------------------------------------------------------------------------
__global__ __launch_bounds__(256) void gate_v3_kernel(
        const float* __restrict__ xf, const float* __restrict__ yf,
        const float* __restrict__ W1, const float* __restrict__ b1,
        const float* __restrict__ W2, const float* __restrict__ b2,
        int4* __restrict__ rec, const int* __restrict__ nmask,
        float* __restrict__ wout) {
    __shared__ float As[2][GBM][32];
    __shared__ float Bs[2][H_DIM][33];
    __shared__ float hbuf[GBM][132];
    __shared__ int   elds[GBM];

    int n  = *nmask;
    int b0 = blockIdx.x * GBM;
    if (b0 >= n) return;

    int t = threadIdx.x;
    if (t < GBM) {
        int idx = b0 + t;
        elds[t] = (idx < n) ? rec[idx].z : rec[b0].z;
    }
    __syncthreads();

    const int  arow = t >> 3;
    const int  acol = (t & 7) * 4;
    const bool aact = (t < 128);
    const int  brow = t >> 3;
    const int  bcol = (t & 7) * 4;

    const float* xrow = xf + (size_t)elds[aact ? arow : 0] * D_FEAT + acol;
    const float* yrow = yf + (size_t)elds[aact ? arow : 0] * D_FEAT + acol;
    const float* w1p0 = W1 + (size_t)(brow +  0) * K2 + bcol;
    const float* w1p1 = W1 + (size_t)(brow + 32) * K2 + bcol;
    const float* w1p2 = W1 + (size_t)(brow + 64) * K2 + bcol;
    const float* w1p3 = W1 + (size_t)(brow + 96) * K2 + bcol;

    float4 aR = make_float4(0.f, 0.f, 0.f, 0.f);
    float4 bR0, bR1, bR2, bR3;

    if (aact) aR = *(const float4*)(xrow + 0);
    bR0 = *(const float4*)(w1p0 + 0);
    bR1 = *(const float4*)(w1p1 + 0);
    bR2 = *(const float4*)(w1p2 + 0);
    bR3 = *(const float4*)(w1p3 + 0);
    if (aact) *(float4*)(&As[0][arow][acol]) = aR;
    Bs[0][brow +  0][bcol + 0] = bR0.x; Bs[0][brow +  0][bcol + 1] = bR0.y;
    Bs[0][brow +  0][bcol + 2] = bR0.z; Bs[0][brow +  0][bcol + 3] = bR0.w;
    Bs[0][brow + 32][bcol + 0] = bR1.x; Bs[0][brow + 32][bcol + 1] = bR1.y;
    Bs[0][brow + 32][bcol + 2] = bR1.z; Bs[0][brow + 32][bcol + 3] = bR1.w;
    Bs[0][brow + 64][bcol + 0] = bR2.x; Bs[0][brow + 64][bcol + 1] = bR2.y;
    Bs[0][brow + 64][bcol + 2] = bR2.z; Bs[0][brow + 64][bcol + 3] = bR2.w;
    Bs[0][brow + 96][bcol + 0] = bR3.x; Bs[0][brow + 96][bcol + 1] = bR3.y;
    Bs[0][brow + 96][bcol + 2] = bR3.z; Bs[0][brow + 96][bcol + 3] = bR3.w;
    __syncthreads();

    const int eb = (t >> 6) * 4;
    const int ln = t & 63;
    float acc[4][2] = {{0.f,0.f},{0.f,0.f},{0.f,0.f},{0.f,0.f}};

    const int NT = K2 / 32;
    for (int tile = 0; tile < NT; ++tile) {
        const int buf = tile & 1;
        if (tile + 1 < NT) {
            int k0 = (tile + 1) * 32;
            if (aact) {
                const float* ap = (k0 < D_FEAT) ? (xrow + k0) : (yrow + (k0 - D_FEAT));
                aR = *(const float4*)ap;
            }
            bR0 = *(const float4*)(w1p0 + k0);
            bR1 = *(const float4*)(w1p1 + k0);
            bR2 = *(const float4*)(w1p2 + k0);
            bR3 = *(const float4*)(w1p3 + k0);
        }
#pragma unroll
        for (int kk = 0; kk < 32; kk += 4) {
            float4 a0 = *(const float4*)(&As[buf][eb + 0][kk]);
            float4 a1 = *(const float4*)(&As[buf][eb + 1][kk]);
            float4 a2 = *(const float4*)(&As[buf][eb + 2][kk]);
            float4 a3 = *(const float4*)(&As[buf][eb + 3][kk]);
            float bl0 = Bs[buf][ln][kk + 0];
            float bl1 = Bs[buf][ln][kk + 1];
            float bl2 = Bs[buf][ln][kk + 2];
            float bl3 = Bs[buf][ln][kk + 3];
            float bh0 = Bs[buf][ln + 64][kk + 0];
            float bh1 = Bs[buf][ln + 64][kk + 1];
            float bh2 = Bs[buf][ln + 64][kk + 2];
            float bh3 = Bs[buf][ln + 64][kk + 3];
            acc[0][0] = fmaf(a0.x, bl0, acc[0][0]);
            acc[0][0] = fmaf(a0.y, bl1, acc[0][0]);
            acc[0][0] = fmaf(a0.z, bl2, acc[0][0]);
            acc[0][0] = fmaf(a0.w, bl3, acc[0][0]);
            acc[0][1] = fmaf(a0.x, bh0, acc[0][1]);
            acc[0][1] = fmaf(a0.y, bh1, acc[0][1]);
            acc[0][1] = fmaf(a0.z, bh2, acc[0][1]);
            acc[0][1] = fmaf(a0.w, bh3, acc[0][1]);
            acc[1][0] = fmaf(a1.x, bl0, acc[1][0]);
            acc[1][0] = fmaf(a1.y, bl1, acc[1][0]);
            acc[1][0] = fmaf(a1.z, bl2, acc[1][0]);
            acc[1][0] = fmaf(a1.w, bl3, acc[1][0]);
            acc[1][1] = fmaf(a1.x, bh0, acc[1][1]);
            acc[1][1] = fmaf(a1.y, bh1, acc[1][1]);
            acc[1][1] = fmaf(a1.z, bh2, acc[1][1]);
            acc[1][1] = fmaf(a1.w, bh3, acc[1][1]);
            acc[2][0] = fmaf(a2.x, bl0, acc[2][0]);
            acc[2][0] = fmaf(a2.y, bl1, acc[2][0]);
            acc[2][0] = fmaf(a2.z, bl2, acc[2][0]);
            acc[2][0] = fmaf(a2.w, bl3, acc[2][0]);
            acc[2][1] = fmaf(a2.x, bh0, acc[2][1]);
            acc[2][1] = fmaf(a2.y, bh1, acc[2][1]);
            acc[2][1] = fmaf(a2.z, bh2, acc[2][1]);
            acc[2][1] = fmaf(a2.w, bh3, acc[2][1]);
            acc[3][0] = fmaf(a3.x, bl0, acc[3][0]);
            acc[3][0] = fmaf(a3.y, bl1, acc[3][0]);
            acc[3][0] = fmaf(a3.z, bl2, acc[3][0]);
            acc[3][0] = fmaf(a3.w, bl3, acc[3][0]);
            acc[3][1] = fmaf(a3.x, bh0, acc[3][1]);
            acc[3][1] = fmaf(a3.y, bh1, acc[3][1]);
            acc[3][1] = fmaf(a3.z, bh2, acc[3][1]);
            acc[3][1] = fmaf(a3.w, bh3, acc[3][1]);
        }
        if (tile + 1 < NT) {
            const int nb = buf ^ 1;
            if (aact) *(float4*)(&As[nb][arow][acol]) = aR;
            Bs[nb][brow +  0][bcol + 0] = bR0.x; Bs[nb][brow +  0][bcol + 1] = bR0.y;
            Bs[nb][brow +  0][bcol + 2] = bR0.z; Bs[nb][brow +  0][bcol + 3] = bR0.w;
            Bs[nb][brow + 32][bcol + 0] = bR1.x; Bs[nb][brow + 32][bcol + 1] = bR1.y;
            Bs[nb][brow + 32][bcol + 2] = bR1.z; Bs[nb][brow + 32][bcol + 3] = bR1.w;
            Bs[nb][brow + 64][bcol + 0] = bR2.x; Bs[nb][brow + 64][bcol + 1] = bR2.y;
            Bs[nb][brow + 64][bcol + 2] = bR2.z; Bs[nb][brow + 64][bcol + 3] = bR2.w;
            Bs[nb][brow + 96][bcol + 0] = bR3.x; Bs[nb][brow + 96][bcol + 1] = bR3.y;
            Bs[nb][brow + 96][bcol + 2] = bR3.z; Bs[nb][brow + 96][bcol + 3] = bR3.w;
        }
        __syncthreads();
    }

#pragma unroll
    for (int j = 0; j < 4; ++j) {
        hbuf[eb + j][ln]      = fmaxf(acc[j][0] + b1[ln], 0.f);
        hbuf[eb + j][ln + 64] = fmaxf(acc[j][1] + b1[ln + 64], 0.f);
    }
    __syncthreads();
    if (t < GBM && b0 + t < n) {
        float s = 0.f;
        for (int c = 0; c < 32; ++c) {
            float p = 0.f;
#pragma unroll
            for (int q = 0; q < 4; ++q)
                p = fmaf(hbuf[t][4 * c + q], W2[4 * c + q], p);
            s += p;
        }
        float logit = s + b2[0];
        float attn  = 1.f / (1.f + expf(-logit));
        wout[elds[t]] = attn;
        ((int*)&rec[b0 + t])[3] = __float_as_int(attn);
    }
}

// ---------------------------------------------------------------------------
// Kernel 7: CC labels (min-label fixpoint in LDS) -> per-EDGE labels elab[].
// ---------------------------------------------------------------------------
__global__ __launch_bounds__(1024) void label_kernel(
        const int4* __restrict__ rec, const int* __restrict__ nmask,
        int* __restrict__ elab) {
    extern __shared__ int L[];
    int t = threadIdx.x;
    int n = *nmask;
    for (int c = t; c < NSLOTS; c += 1024) L[c] = c;
    __syncthreads();
    for (;;) {
        if (t == 0) L[NSLOTS] = 0;
        __syncthreads();
        for (int e = t; e < n; e += 1024) {
            int4 r = rec[e];
            int a = L[r.x], b = L[r.y];
            if (a < b)      { atomicMin(&L[r.y], a); L[NSLOTS] = 1; }
            else if (b < a) { atomicMin(&L[r.x], b); L[NSLOTS] = 1; }
        }
        __syncthreads();
        if (!L[NSLOTS]) break;
        __syncthreads();
        for (int c = t; c < NSLOTS; c += 1024) {
            int q  = L[c];
            int qq = L[q];
            if (qq < q) L[c] = qq;
        }
        __syncthreads();
    }
    __syncthreads();
    for (int e = t; e < n; e += 1024) elab[e] = L[rec[e].x];
}

// ---------------------------------------------------------------------------
// Kernel 8: stable LSD radix sort of edges by CC label (4 passes x 4 bits),
//   single block, 1024 threads; then boundary extraction.
// ---------------------------------------------------------------------------
__global__ __launch_bounds__(1024) void radix_kernel(
        int4* __restrict__ bufA, int4* __restrict__ bufB,
        int* __restrict__ keyA, int* __restrict__ keyB,
        const int* __restrict__ nmask,
        int* __restrict__ compStart, int* __restrict__ ncompOut) {
    __shared__ int F[16384];
    __shared__ int P[1024];
    int t = threadIdx.x;
    int n = *nmask;
    int c = (n + 1023) >> 10;

    for (int pass = 0; pass < 4; ++pass) {
        int sh = pass * 4;
        const int4* in   = (pass & 1) ? bufB : bufA;
        int4*       out  = (pass & 1) ? bufA : bufB;
        const int*  kin  = (pass & 1) ? keyB : keyA;
        int*        kout = (pass & 1) ? keyA : keyB;
        for (int q = 0; q < 16; ++q) F[t * 16 + q] = 0;
        __syncthreads();
        for (int j = 0; j < c; ++j) {
            int i = t * c + j;
            if (i < n) {
                int d = (kin[i] >> sh) & 15;
                F[d * 1024 + t] += 1;
            }
        }
        __syncthreads();
        int base = t * 16;
        int loc[16]; int s = 0;
#pragma unroll
        for (int q = 0; q < 16; ++q) { loc[q] = s; s += F[base + q]; }
        P[t] = s;
        __syncthreads();
        for (int off = 1; off < 1024; off <<= 1) {
            int mine  = P[t];
            int other = (t >= off) ? P[t - off] : 0;
            __syncthreads();
            P[t] = mine + other;
            __syncthreads();
        }
        int pre = (t == 0) ? 0 : P[t - 1];
#pragma unroll
        for (int q = 0; q < 16; ++q) F[base + q] = pre + loc[q];
        __syncthreads();
        for (int j = 0; j < c; ++j) {
            int i = t * c + j;
            if (i < n) {
                int k = kin[i];
                int d = (k >> sh) & 15;
                int pos = F[d * 1024 + t]++;
                out[pos]  = in[i];
                kout[pos] = k;
            }
        }
        __syncthreads();
    }

    unsigned char* hd = (unsigned char*)F;
    for (int i = t; i < n; i += 1024) {
        int l  = keyA[i];
        int lp = (i == 0) ? -1 : keyA[i - 1];
        hd[i] = (l != lp) ? 1 : 0;
    }
    __syncthreads();
    int hsum = 0;
    for (int j = 0; j < c; ++j) {
        int i = t * c + j;
        if (i < n) hsum += hd[i];
    }
    P[t] = hsum;
    __syncthreads();
    for (int off = 1; off < 1024; off <<= 1) {
        int mine  = P[t];
        int other = (t >= off) ? P[t - off] : 0;
        __syncthreads();
        P[t] = mine + other;
        __syncthreads();
    }
    int run = P[t] - hsum;
    for (int j = 0; j < c; ++j) {
        int i = t * c + j;
        if (i < n && hd[i]) { compStart[run] = i; ++run; }
    }
    if (t == 1023) { int total = P[1023]; *ncompOut = total; compStart[total] = n; }
}

// ---------------------------------------------------------------------------
// Kernel 9: exact union-find, parallel over connected components.
// ---------------------------------------------------------------------------
__global__ __launch_bounds__(1024) void uf_kernel(
        const int4* __restrict__ srec, const int* __restrict__ ncompPtr,
        const int* __restrict__ compStart,
        const int* __restrict__ orig, const float* __restrict__ rin,
        int* __restrict__ gpar, float* __restrict__ grank) {
    extern __shared__ char smem[];
    int2* nd = (int2*)smem;
    int* ndw = (int*)smem;
    int t = threadIdx.x;
    for (int c = t; c < NSLOTS; c += 1024) {
        int o = orig[c];
        float r = (o >= 0) ? rin[o] : 1.0f;
        nd[c] = make_int2(c, __float_as_int(r));
    }
    __syncthreads();

    int ncomp = *ncompPtr;
    for (int c = t; c < ncomp; c += 1024) {
        int s  = compStart[c];
        int en = compStart[c + 1];
        for (int j = s; j < en; ++j) {
            int4 r = srec[j];
            int x = r.x, y = r.y;
            float wi = __int_as_float(r.w);
            int p;
            int rx = x;
            while ((p = ndw[rx * 2]) != rx) rx = p;
            int j2 = x;
            while ((p = ndw[j2 * 2]) != rx) { ndw[j2 * 2] = rx; j2 = p; }
            int ry = y;
            while ((p = ndw[ry * 2]) != ry) ry = p;
            j2 = y;
            while ((p = ndw[j2 * 2]) != ry) { ndw[j2 * 2] = ry; j2 = p; }
            if (rx != ry) {
                float ka = __int_as_float(ndw[rx * 2 + 1]);
                float kb = __int_as_float(ndw[ry * 2 + 1]);
                bool bx = ka > kb;
                int big = bx ? rx : ry, small = bx ? ry : rx;
                float nr = bx ? (ka + kb * wi) : (kb + ka * wi);
                ndw[small * 2]   = big;
                ndw[big * 2 + 1] = __float_as_int(nr);
            }
        }
    }
    __syncthreads();
    for (int c = t; c < NSLOTS; c += 1024) {
        int2 v = nd[c];
        gpar[c] = v.x;
        grank[c] = __int_as_float(v.y);
    }
}

// ---------------------------------------------------------------------------
// Kernel 10: finalize — per node, claimed -> compact result, else input copy.
// ---------------------------------------------------------------------------
__global__ void finalize_kernel(const int* __restrict__ pin, const float* __restrict__ rin,
                                const int* __restrict__ fo, const int* __restrict__ orig,
                                const int* __restrict__ gpar, const float* __restrict__ grank,
                                float* __restrict__ pout, float* __restrict__ rout) {
    int i = blockIdx.x * blockDim.x + threadIdx.x;
    if (i >= N_NODES) return;
    int c = fo[i];
    float pv, rv;
    if (c != 0x7FFFFFFF) {
        pv = (float)orig[gpar[c]];
        rv = grank[c];
    } else {
        pv = (float)pin[i];
        rv = rin[i];
    }
    pout[i] = pv;
    rout[i] = rv;
}

// ---------------------------------------------------------------------------
extern "C" void kernel_launch(void* const* d_in, const int* in_sizes, int n_in,
                              void* d_out, int out_size, void* d_ws, size_t ws_size,
                              hipStream_t stream) {
    const int*   x_idx = (const int*)d_in[0];
    const int*   y_idx = (const int*)d_in[1];
    const float* xf    = (const float*)d_in[2];
    const float* yf    = (const float*)d_in[3];
    const float* W1    = (const float*)d_in[4];
    const float* b1    = (const float*)d_in[5];
    const float* W2    = (const float*)d_in[6];
    const float* b2    = (const float*)d_in[7];
    const int*   pin   = (const int*)d_in[8];
    const float* rin   = (const float*)d_in[9];

    float* out   = (float*)d_out;
    float* w_out = out;                        // [E]
    float* pout  = out + E_EDGES;              // [N]
    float* rout  = out + E_EDGES + N_NODES;    // [N]

    char* ws = (char*)d_ws;
    float* sim_ws  = (float*)(ws + 0);         //  32768 B (later: keyA)
    int*   fo      = (int*)  (ws + 32768);     // 400000 B
    int*   orig    = (int*)  (ws + 432768);    //  65536 B
    int4*  rec     = (int4*) (ws + 498304);    // 131136 B  (8192+4 recs)
    int*   nmask   = (int*)  (ws + 629440);    //     64 B
    int*   gpar    = (int*)  (ws + 629504);    //  65536 B
    float* grank   = (float*)(ws + 695040);    //  65536 B
    int4*  srec    = (int4*) (ws + 760576);    // 131072 B (radix scratch)
    int*   keyB    = (int*)  (ws + 891648);    //  32768 B
    int*   compSt  = (int*)  (ws + 924416);    //  32772 B (8193 ints)
    int*   ncomp   = (int*)  (ws + 957188);    //      4 B
    float* pbuf    = (float*)(ws + 957440);    // 4.2 MB partials (if ws allows)
    int*   keyA    = (int*)sim_ws;             // overlay: sim consumed by maskscan

    const size_t need2 = 957440 + (size_t)E_EDGES * 2 * 128 * sizeof(float);

    // 1) cosine sim + fused init of fo/orig/w
    sim_kernel<<<(E_EDGES * 64) / 256, 256, 0, stream>>>(xf, yf, sim_ws,
                                                         fo, orig, w_out);
    // 2) compact-id mapping
    int g = (N_NODES + 255) / 256;
    claim_kernel<<<NSLOTS / 256, 256, 0, stream>>>(x_idx, y_idx, fo);
    orig_kernel<<<NSLOTS / 256, 256, 0, stream>>>(x_idx, y_idx, fo, orig);
    // 3) masked-edge compaction (records + padding)
    maskscan_kernel<<<1, 256, 0, stream>>>(x_idx, y_idx, fo, sim_ws, rec, nmask);
    // 4) gate MLP over masked edges (K-split x2 or fallback)
    if (ws_size >= need2) {
        dim3 gg(E_EDGES / GBM, 2);
        gate_split_kernel<<<gg, 256, 0, stream>>>(xf, yf, W1, rec, nmask, pbuf);
        gate_fin_kernel<<<E_EDGES / 256, 256, 0, stream>>>(pbuf, b1, W2, b2,
                                                           rec, nmask, w_out);
    } else {
        gate_v3_kernel<<<E_EDGES / GBM, 256, 0, stream>>>(xf, yf, W1, b1, W2, b2,
                                                          rec, nmask, w_out);
    }
    // 5) CC labels per edge (deterministic min-label fixpoint)
    label_kernel<<<1, 1024, (NSLOTS + 1) * sizeof(int), stream>>>(rec, nmask, keyA);
    // 6) stable radix sort by label + boundaries (single block)
    radix_kernel<<<1, 1024, 0, stream>>>(rec, srec, keyA, keyB, nmask, compSt, ncomp);
    // 7) exact UF, parallel over components (LDS 128 KB); sorted edges in rec
    uf_kernel<<<1, 1024, 131072, stream>>>(rec, ncomp, compSt, orig, rin, gpar, grank);
    // 8) finalize outputs (base copy + compact scatter fused)
    finalize_kernel<<<g, 256, 0, stream>>>(pin, rin, fo, orig, gpar, grank, pout, rout);
}